// Round 1
// baseline (355.611 us; speedup 1.0000x reference)
//
#include <hip/hip_runtime.h>

#define INF __builtin_inff()

typedef __attribute__((ext_vector_type(8))) short bf16x8;
typedef __attribute__((ext_vector_type(4))) float f32x4;
typedef __attribute__((ext_vector_type(4))) unsigned int u32x4;
typedef __attribute__((ext_vector_type(8))) unsigned short u16x8;

#define MFMA16(a, b, c) __builtin_amdgcn_mfma_f32_16x16x32_bf16(a, b, c, 0, 0, 0)

__device__ __forceinline__ unsigned short f2bf(float f) {
  union { float f; unsigned u; } v; v.f = f;
  unsigned r = v.u + 0x7fffu + ((v.u >> 16) & 1u);   // RNE
  return (unsigned short)(r >> 16);
}
__device__ __forceinline__ float bf2f(unsigned short u) {
  union { unsigned u; float f; } v; v.u = ((unsigned)u) << 16;
  return v.f;
}

// ---------- fp32 -> bf16 elementwise (8 elems / thread) ----------
__global__ void k_cvt(const float* __restrict__ src, unsigned short* __restrict__ dst, int n8) {
  int i = blockIdx.x * blockDim.x + threadIdx.x;
  if (i >= n8) return;
  const float4* s = (const float4*)src + (size_t)i * 2;
  float4 a = s[0], b = s[1];
  u16x8 o;
  o[0] = f2bf(a.x); o[1] = f2bf(a.y); o[2] = f2bf(a.z); o[3] = f2bf(a.w);
  o[4] = f2bf(b.x); o[5] = f2bf(b.y); o[6] = f2bf(b.z); o[7] = f2bf(b.w);
  ((u16x8*)dst)[i] = o;
}

// ---------- fp32 [R][C] -> bf16 [C][R] transpose+convert ----------
__global__ __launch_bounds__(256) void k_transpose_cvt(
    const float* __restrict__ src, unsigned short* __restrict__ dst, int R, int C) {
  __shared__ float tile[32][33];
  int bc = blockIdx.x * 32;          // col base in src
  int br = blockIdx.y * 32;          // row base in src
  int tx = threadIdx.x & 31, ty = threadIdx.x >> 5;   // 32 x 8
#pragma unroll
  for (int i = 0; i < 32; i += 8)
    tile[ty + i][tx] = src[(size_t)(br + ty + i) * C + bc + tx];
  __syncthreads();
#pragma unroll
  for (int i = 0; i < 32; i += 8)
    dst[(size_t)(bc + ty + i) * R + br + tx] = f2bf(tile[tx][ty + i]);
}

// ---------- GEMM1: qkv = x @ w_qkv, scattered into q / k / v^T ----------
// A [4096][1024] bf16, Bt [3072][1024] bf16 (w_qkv transposed)
__global__ __launch_bounds__(256) void k_gemm_qkv(
    const unsigned short* __restrict__ A, const unsigned short* __restrict__ Bt,
    unsigned short* __restrict__ qb, unsigned short* __restrict__ kb,
    unsigned short* __restrict__ vt) {
  const int K = 1024;
  __shared__ unsigned short As[128 * 32];
  __shared__ unsigned short Bs[128 * 32];
  const int t = threadIdx.x;
  const int lane = t & 63, wave = t >> 6;
  const int bm0 = blockIdx.y * 128, bn0 = blockIdx.x * 128;
  const int wm = (wave >> 1) * 64, wn = (wave & 1) * 64;
  const int lr = lane & 15, q8 = (lane >> 4) * 8;
  f32x4 acc[4][4] = {};
  for (int k0 = 0; k0 < K; k0 += 32) {
#pragma unroll
    for (int it = 0; it < 2; ++it) {
      int idx = t + it * 256;
      int r = idx >> 2, cg = (idx & 3) * 8;
      *(u32x4*)(&As[r * 32 + cg]) = *(const u32x4*)(&A[(size_t)(bm0 + r) * K + k0 + cg]);
      *(u32x4*)(&Bs[r * 32 + cg]) = *(const u32x4*)(&Bt[(size_t)(bn0 + r) * K + k0 + cg]);
    }
    __syncthreads();
    bf16x8 af[4], bfr[4];
#pragma unroll
    for (int i = 0; i < 4; ++i) af[i] = *(const bf16x8*)(&As[(wm + i * 16 + lr) * 32 + q8]);
#pragma unroll
    for (int j = 0; j < 4; ++j) bfr[j] = *(const bf16x8*)(&Bs[(wn + j * 16 + lr) * 32 + q8]);
#pragma unroll
    for (int i = 0; i < 4; ++i)
#pragma unroll
      for (int j = 0; j < 4; ++j)
        acc[i][j] = MFMA16(af[i], bfr[j], acc[i][j]);
    __syncthreads();
  }
  const int lq4 = (lane >> 4) * 4;
#pragma unroll
  for (int i = 0; i < 4; ++i) {
#pragma unroll
    for (int j = 0; j < 4; ++j) {
#pragma unroll
      for (int r = 0; r < 4; ++r) {
        int row = bm0 + wm + i * 16 + lq4 + r;   // token 0..4095
        int col = bn0 + wn + j * 16 + lr;        // 0..3071
        unsigned short v = f2bf(acc[i][j][r]);
        int b = row >> 10, n = row & 1023;
        int sec = col >> 10, js = col & 1023;
        int h = js >> 6, d = js & 63;
        size_t bh = (size_t)(b * 16 + h);
        if (sec == 0)      qb[(bh * 1024 + n) * 64 + d] = v;
        else if (sec == 1) kb[(bh * 1024 + n) * 64 + d] = v;
        else               vt[(bh * 64 + d) * 1024 + n] = v;   // V transposed [DH][N]
      }
    }
  }
}

// ---------- Attention: one wave per (b,h,16-row q tile) ----------
__global__ __launch_bounds__(64) void k_attn(
    const unsigned short* __restrict__ qb, const unsigned short* __restrict__ kb,
    const unsigned short* __restrict__ vt, const float* __restrict__ mask,
    unsigned short* __restrict__ ao) {
  __shared__ unsigned short S[16 * 1024];   // score row tile, bf16
  __shared__ float mk[1024];
  const int bid = blockIdx.x;
  const int qt = bid & 63, h = (bid >> 6) & 15, b = bid >> 10;
  const int q0 = qt * 16;
  const int l = threadIdx.x, lr = l & 15, quad = l >> 4;
  const unsigned short* qp = qb + ((size_t)(b * 16 + h) << 16);  // N*DH = 65536
  const unsigned short* kp = kb + ((size_t)(b * 16 + h) << 16);
  const unsigned short* vp = vt + ((size_t)(b * 16 + h) << 16);
#pragma unroll
  for (int i = 0; i < 16; ++i) mk[l + i * 64] = mask[b * 1024 + l + i * 64];
  __syncthreads();
  // Q fragments (held for whole phase 1)
  bf16x8 a0 = *(const bf16x8*)(qp + (q0 + lr) * 64 + quad * 8);
  bf16x8 a1 = *(const bf16x8*)(qp + (q0 + lr) * 64 + 32 + quad * 8);
  float mq[4];
#pragma unroll
  for (int r = 0; r < 4; ++r) mq[r] = mk[q0 + quad * 4 + r];
  // ---- phase 1: S = mask(QK^T * scale), bf16 into LDS
  for (int m0 = 0; m0 < 1024; m0 += 16) {
    bf16x8 b0 = *(const bf16x8*)(kp + (m0 + lr) * 64 + quad * 8);
    bf16x8 b1 = *(const bf16x8*)(kp + (m0 + lr) * 64 + 32 + quad * 8);
    f32x4 c = {};
    c = MFMA16(a0, b0, c);
    c = MFMA16(a1, b1, c);
    float mkv = mk[m0 + lr];
#pragma unroll
    for (int r = 0; r < 4; ++r) {
      float s = (mq[r] * mkv != 0.f) ? c[r] * 0.125f : -INF;
      S[(quad * 4 + r) * 1024 + m0 + lr] = f2bf(s);
    }
  }
  __syncthreads();
  // ---- phase 2: softmax per row; 4 lanes per row, 256 cols each
  unsigned short* Srow = &S[lr * 1024 + quad * 256];
  float mx = -INF;
  for (int c = 0; c < 256; c += 8) {
    bf16x8 v = *(const bf16x8*)(Srow + c);
#pragma unroll
    for (int j = 0; j < 8; ++j) mx = fmaxf(mx, bf2f((unsigned short)v[j]));
  }
  mx = fmaxf(mx, __shfl_xor(mx, 16));
  mx = fmaxf(mx, __shfl_xor(mx, 32));
  const bool valid = (mx != -INF);   // fully-masked row -> attn = 0
  float sum = 0.f;
  for (int c = 0; c < 256; c += 8) {
    bf16x8 v = *(const bf16x8*)(Srow + c);
#pragma unroll
    for (int j = 0; j < 8; ++j)
      sum += valid ? __expf(bf2f((unsigned short)v[j]) - mx) : 0.f;
  }
  sum += __shfl_xor(sum, 16);
  sum += __shfl_xor(sum, 32);
  const float inv = valid ? 1.f / sum : 0.f;
  for (int c = 0; c < 256; c += 8) {
    bf16x8 v = *(const bf16x8*)(Srow + c);
    u16x8 w;
#pragma unroll
    for (int j = 0; j < 8; ++j) {
      float p = valid ? __expf(bf2f((unsigned short)v[j]) - mx) * inv : 0.f;
      w[j] = f2bf(p);
    }
    *(u16x8*)(Srow + c) = w;
  }
  __syncthreads();
  // ---- phase 3: O = P @ V  (V stored transposed: b-frag m-contiguous)
  f32x4 o[4] = {};
  for (int m0 = 0; m0 < 1024; m0 += 32) {
    bf16x8 a = *(const bf16x8*)(&S[lr * 1024 + m0 + quad * 8]);
#pragma unroll
    for (int jj = 0; jj < 4; ++jj) {
      bf16x8 bv = *(const bf16x8*)(vp + (jj * 16 + lr) * 1024 + m0 + quad * 8);
      o[jj] = MFMA16(a, bv, o[jj]);
    }
  }
  const int tok0 = b * 1024 + q0 + quad * 4;
#pragma unroll
  for (int jj = 0; jj < 4; ++jj)
#pragma unroll
    for (int r = 0; r < 4; ++r)
      ao[(size_t)(tok0 + r) * 1024 + h * 64 + jj * 16 + lr] = f2bf(o[jj][r]);
}

// ---------- GEMM2: out = attn_out @ w_out + b_out (fp32 out) ----------
__global__ __launch_bounds__(256) void k_gemm_out(
    const unsigned short* __restrict__ A, const unsigned short* __restrict__ Bt,
    const float* __restrict__ bias, float* __restrict__ C) {
  const int K = 1024;
  __shared__ unsigned short As[128 * 32];
  __shared__ unsigned short Bs[128 * 32];
  const int t = threadIdx.x;
  const int lane = t & 63, wave = t >> 6;
  const int bm0 = blockIdx.y * 128, bn0 = blockIdx.x * 128;
  const int wm = (wave >> 1) * 64, wn = (wave & 1) * 64;
  const int lr = lane & 15, q8 = (lane >> 4) * 8;
  f32x4 acc[4][4] = {};
  for (int k0 = 0; k0 < K; k0 += 32) {
#pragma unroll
    for (int it = 0; it < 2; ++it) {
      int idx = t + it * 256;
      int r = idx >> 2, cg = (idx & 3) * 8;
      *(u32x4*)(&As[r * 32 + cg]) = *(const u32x4*)(&A[(size_t)(bm0 + r) * K + k0 + cg]);
      *(u32x4*)(&Bs[r * 32 + cg]) = *(const u32x4*)(&Bt[(size_t)(bn0 + r) * K + k0 + cg]);
    }
    __syncthreads();
    bf16x8 af[4], bfr[4];
#pragma unroll
    for (int i = 0; i < 4; ++i) af[i] = *(const bf16x8*)(&As[(wm + i * 16 + lr) * 32 + q8]);
#pragma unroll
    for (int j = 0; j < 4; ++j) bfr[j] = *(const bf16x8*)(&Bs[(wn + j * 16 + lr) * 32 + q8]);
#pragma unroll
    for (int i = 0; i < 4; ++i)
#pragma unroll
      for (int j = 0; j < 4; ++j)
        acc[i][j] = MFMA16(af[i], bfr[j], acc[i][j]);
    __syncthreads();
  }
  const int lq4 = (lane >> 4) * 4;
#pragma unroll
  for (int i = 0; i < 4; ++i)
#pragma unroll
    for (int j = 0; j < 4; ++j)
#pragma unroll
      for (int r = 0; r < 4; ++r) {
        int row = bm0 + wm + i * 16 + lq4 + r;
        int col = bn0 + wn + j * 16 + lr;
        C[(size_t)row * 1024 + col] = acc[i][j][r] + bias[col];
      }
}

extern "C" void kernel_launch(void* const* d_in, const int* in_sizes, int n_in,
                              void* d_out, int out_size, void* d_ws, size_t ws_size,
                              hipStream_t stream) {
  const float* x    = (const float*)d_in[0];
  const float* mask = (const float*)d_in[1];
  const float* wqkv = (const float*)d_in[2];
  const float* wout = (const float*)d_in[3];
  const float* bout = (const float*)d_in[4];
  float* out = (float*)d_out;
  char* ws = (char*)d_ws;
  // workspace layout (48 MB total)
  unsigned short* xbf   = (unsigned short*)(ws);                     // 8 MB  [4096][1024]
  unsigned short* wqkvt = (unsigned short*)(ws + (size_t)( 8 << 20)); // 6 MB  [3072][1024]
  unsigned short* woutt = (unsigned short*)(ws + (size_t)(14 << 20)); // 2 MB  [1024][1024]
  unsigned short* qb    = (unsigned short*)(ws + (size_t)(16 << 20)); // 8 MB  [B][H][N][DH]
  unsigned short* kb    = (unsigned short*)(ws + (size_t)(24 << 20)); // 8 MB  [B][H][N][DH]
  unsigned short* vt    = (unsigned short*)(ws + (size_t)(32 << 20)); // 8 MB  [B][H][DH][N]
  unsigned short* ao    = (unsigned short*)(ws + (size_t)(40 << 20)); // 8 MB  [4096][1024]

  k_cvt<<<2048, 256, 0, stream>>>(x, xbf, 524288);
  k_transpose_cvt<<<dim3(96, 32), 256, 0, stream>>>(wqkv, wqkvt, 1024, 3072);
  k_transpose_cvt<<<dim3(32, 32), 256, 0, stream>>>(wout, woutt, 1024, 1024);
  k_gemm_qkv<<<dim3(24, 32), 256, 0, stream>>>(xbf, wqkvt, qb, kb, vt);
  k_attn<<<4096, 64, 0, stream>>>(qb, kb, vt, mask, ao);
  k_gemm_out<<<dim3(8, 32), 256, 0, stream>>>(ao, woutt, bout, out);
}

// Round 2
// 294.122 us; speedup vs baseline: 1.2091x; 1.2091x over previous
//
#include <hip/hip_runtime.h>

#define INF __builtin_inff()

typedef __attribute__((ext_vector_type(8))) short bf16x8;
typedef __attribute__((ext_vector_type(4))) short s16x4;
typedef __attribute__((ext_vector_type(4))) float f32x4;
typedef __attribute__((ext_vector_type(4))) unsigned int u32x4;
typedef __attribute__((ext_vector_type(8))) unsigned short u16x8;

#define MFMA16(a, b, c) __builtin_amdgcn_mfma_f32_16x16x32_bf16(a, b, c, 0, 0, 0)

__device__ __forceinline__ unsigned short f2bf(float f) {
  union { float f; unsigned u; } v; v.f = f;
  unsigned r = v.u + 0x7fffu + ((v.u >> 16) & 1u);   // RNE
  return (unsigned short)(r >> 16);
}
__device__ __forceinline__ float bf2f(unsigned short u) {
  union { unsigned u; float f; } v; v.u = ((unsigned)u) << 16;
  return v.f;
}

// ---------- fp32 -> bf16 elementwise (8 elems / thread) ----------
__global__ void k_cvt(const float* __restrict__ src, unsigned short* __restrict__ dst, int n8) {
  int i = blockIdx.x * blockDim.x + threadIdx.x;
  if (i >= n8) return;
  const float4* s = (const float4*)src + (size_t)i * 2;
  float4 a = s[0], b = s[1];
  u16x8 o;
  o[0] = f2bf(a.x); o[1] = f2bf(a.y); o[2] = f2bf(a.z); o[3] = f2bf(a.w);
  o[4] = f2bf(b.x); o[5] = f2bf(b.y); o[6] = f2bf(b.z); o[7] = f2bf(b.w);
  ((u16x8*)dst)[i] = o;
}

// ---------- fp32 [R][C] -> bf16 [C][R] transpose+convert ----------
__global__ __launch_bounds__(256) void k_transpose_cvt(
    const float* __restrict__ src, unsigned short* __restrict__ dst, int R, int C) {
  __shared__ float tile[32][33];
  int bc = blockIdx.x * 32;          // col base in src
  int br = blockIdx.y * 32;          // row base in src
  int tx = threadIdx.x & 31, ty = threadIdx.x >> 5;   // 32 x 8
#pragma unroll
  for (int i = 0; i < 32; i += 8)
    tile[ty + i][tx] = src[(size_t)(br + ty + i) * C + bc + tx];
  __syncthreads();
#pragma unroll
  for (int i = 0; i < 32; i += 8)
    dst[(size_t)(bc + ty + i) * R + br + tx] = f2bf(tile[tx][ty + i]);
}

// ---------- GEMM1: qkv = x @ w_qkv, scattered into q / k / v^T ----------
__global__ __launch_bounds__(256) void k_gemm_qkv(
    const unsigned short* __restrict__ A, const unsigned short* __restrict__ Bt,
    unsigned short* __restrict__ qb, unsigned short* __restrict__ kb,
    unsigned short* __restrict__ vt) {
  const int K = 1024;
  __shared__ unsigned short As[128 * 32];
  __shared__ unsigned short Bs[128 * 32];
  const int t = threadIdx.x;
  const int lane = t & 63, wave = t >> 6;
  const int bm0 = blockIdx.y * 128, bn0 = blockIdx.x * 128;
  const int wm = (wave >> 1) * 64, wn = (wave & 1) * 64;
  const int lr = lane & 15, q8 = (lane >> 4) * 8;
  f32x4 acc[4][4] = {};
  for (int k0 = 0; k0 < K; k0 += 32) {
#pragma unroll
    for (int it = 0; it < 2; ++it) {
      int idx = t + it * 256;
      int r = idx >> 2, cg = (idx & 3) * 8;
      *(u32x4*)(&As[r * 32 + cg]) = *(const u32x4*)(&A[(size_t)(bm0 + r) * K + k0 + cg]);
      *(u32x4*)(&Bs[r * 32 + cg]) = *(const u32x4*)(&Bt[(size_t)(bn0 + r) * K + k0 + cg]);
    }
    __syncthreads();
    bf16x8 af[4], bfr[4];
#pragma unroll
    for (int i = 0; i < 4; ++i) af[i] = *(const bf16x8*)(&As[(wm + i * 16 + lr) * 32 + q8]);
#pragma unroll
    for (int j = 0; j < 4; ++j) bfr[j] = *(const bf16x8*)(&Bs[(wn + j * 16 + lr) * 32 + q8]);
#pragma unroll
    for (int i = 0; i < 4; ++i)
#pragma unroll
      for (int j = 0; j < 4; ++j)
        acc[i][j] = MFMA16(af[i], bfr[j], acc[i][j]);
    __syncthreads();
  }
  const int lq4 = (lane >> 4) * 4;
#pragma unroll
  for (int i = 0; i < 4; ++i) {
#pragma unroll
    for (int j = 0; j < 4; ++j) {
#pragma unroll
      for (int r = 0; r < 4; ++r) {
        int row = bm0 + wm + i * 16 + lq4 + r;   // token 0..4095
        int col = bn0 + wn + j * 16 + lr;        // 0..3071
        unsigned short v = f2bf(acc[i][j][r]);
        int b = row >> 10, n = row & 1023;
        int sec = col >> 10, js = col & 1023;
        int h = js >> 6, d = js & 63;
        size_t bh = (size_t)(b * 16 + h);
        if (sec == 0)      qb[(bh * 1024 + n) * 64 + d] = v;
        else if (sec == 1) kb[(bh * 1024 + n) * 64 + d] = v;
        else               vt[(bh * 64 + d) * 1024 + n] = v;   // V transposed [DH][N]
      }
    }
  }
}

// ---------- Flash attention: 4 waves/block, 16 q-rows/wave, online softmax ----------
// S^T = K·Q^T trick: C-layout of S^T gives each lane contiguous-kc P values for
// its own q; small per-wave LDS round-trip re-shapes P into the x32 A-layout.
__global__ __launch_bounds__(256) void k_attn(
    const unsigned short* __restrict__ qb, const unsigned short* __restrict__ kb,
    const unsigned short* __restrict__ vt, const float* __restrict__ mask,
    unsigned short* __restrict__ ao) {
  __shared__ float bias[1024];                 // 0 where mask!=0, -inf where mask==0
  __shared__ unsigned short P[4][16 * 72];     // per-wave P tile; 144B row stride (bank-floor)
  const int qc = blockIdx.x & 15, bh = blockIdx.x >> 4;
  const int b = bh >> 4, h = bh & 15;
  const int t256 = threadIdx.x;
  const int wave = t256 >> 6, lane = t256 & 63;
  const int lr = lane & 15, quad = lane >> 4;
  const int q0 = qc * 64 + wave * 16;
  const unsigned short* qp = qb + ((size_t)bh << 16);
  const unsigned short* kp = kb + ((size_t)bh << 16);
  const unsigned short* vp = vt + ((size_t)bh << 16);
#pragma unroll
  for (int i = 0; i < 4; ++i) {
    int idx = t256 + i * 256;
    bias[idx] = (mask[b * 1024 + idx] == 0.f) ? -INF : 0.f;
  }
  __syncthreads();
  unsigned short* Pw = P[wave];
  // Q fragments (B-operand: lane holds Q[q=lr][d=quad*8+j])
  bf16x8 qv0 = *(const bf16x8*)(qp + (q0 + lr) * 64 + quad * 8);
  bf16x8 qv1 = *(const bf16x8*)(qp + (q0 + lr) * 64 + 32 + quad * 8);
  float m = -INF, l = 0.f;
  f32x4 o[4] = {};
  for (int kc0 = 0; kc0 < 1024; kc0 += 64) {
    // K fragments: A-operand rows = K rows (4 tiles of 16)
    bf16x8 kf0[4], kf1[4];
#pragma unroll
    for (int t = 0; t < 4; ++t) {
      const unsigned short* kr = kp + (kc0 + t * 16 + lr) * 64 + quad * 8;
      kf0[t] = *(const bf16x8*)(kr);
      kf1[t] = *(const bf16x8*)(kr + 32);
    }
    // S^T tiles: C[kc][q], lane holds kc=quad*4+r, q=lr
    f32x4 st[4];
#pragma unroll
    for (int t = 0; t < 4; ++t) {
      f32x4 c = {};
      c = MFMA16(kf0[t], qv0, c);
      c = MFMA16(kf1[t], qv1, c);
      st[t] = c;
    }
    // masked scores + running tile max (per lane's q column)
    float s[4][4];
    float tm = -INF;
#pragma unroll
    for (int t = 0; t < 4; ++t) {
      float4 bv = *(const float4*)(&bias[kc0 + t * 16 + quad * 4]);
      const float* bvp = (const float*)&bv;
#pragma unroll
      for (int r = 0; r < 4; ++r) {
        float v = fmaf(st[t][r], 0.125f, bvp[r]);
        s[t][r] = v;
        tm = fmaxf(tm, v);
      }
    }
    tm = fmaxf(tm, __shfl_xor(tm, 16));
    tm = fmaxf(tm, __shfl_xor(tm, 32));
    float mn = fmaxf(m, tm);
    bool ok = (mn != -INF);
    float alpha = ok ? __expf(m - mn) : 1.f;
    // P = exp(s - mn), packed bf16, stored to per-wave LDS (P[q][kc] rows)
    float ps = 0.f;
#pragma unroll
    for (int t = 0; t < 4; ++t) {
      s16x4 pv;
#pragma unroll
      for (int r = 0; r < 4; ++r) {
        float pe = ok ? __expf(s[t][r] - mn) : 0.f;
        ps += pe;
        pv[r] = (short)f2bf(pe);
      }
      *(s16x4*)(&Pw[lr * 72 + t * 16 + quad * 4]) = pv;
    }
    ps += __shfl_xor(ps, 16);
    ps += __shfl_xor(ps, 32);
    l = l * alpha + ps;
    m = mn;
    // rescale O (O rows are q=quad*4+r; alpha lives at lane q=lr -> broadcast)
    float ar[4];
#pragma unroll
    for (int r = 0; r < 4; ++r) ar[r] = __shfl(alpha, quad * 4 + r);
#pragma unroll
    for (int jj = 0; jj < 4; ++jj)
#pragma unroll
      for (int r = 0; r < 4; ++r) o[jj][r] *= ar[r];
    // PV: A = P (from LDS, x32 A-layout), B = V^T rows (16B contiguous global)
#pragma unroll
    for (int sh = 0; sh < 2; ++sh) {
      bf16x8 pa = *(const bf16x8*)(&Pw[lr * 72 + sh * 32 + quad * 8]);
#pragma unroll
      for (int jj = 0; jj < 4; ++jj) {
        bf16x8 vb = *(const bf16x8*)(vp + (jj * 16 + lr) * 1024 + kc0 + sh * 32 + quad * 8);
        o[jj] = MFMA16(pa, vb, o[jj]);
      }
    }
  }
  // epilogue: 1/l, zero fully-masked / mq==0 rows, broadcast to C-layout rows
  float inv = (m != -INF) ? 1.f / l : 0.f;
  if (bias[q0 + lr] != 0.f) inv = 0.f;   // q-row masked out
  float ir[4];
#pragma unroll
  for (int r = 0; r < 4; ++r) ir[r] = __shfl(inv, quad * 4 + r);
  const int tok0 = b * 1024 + q0 + quad * 4;
#pragma unroll
  for (int jj = 0; jj < 4; ++jj)
#pragma unroll
    for (int r = 0; r < 4; ++r)
      ao[(size_t)(tok0 + r) * 1024 + h * 64 + jj * 16 + lr] = f2bf(o[jj][r] * ir[r]);
}

// ---------- GEMM2: out = attn_out @ w_out + b_out (fp32 out) ----------
__global__ __launch_bounds__(256) void k_gemm_out(
    const unsigned short* __restrict__ A, const unsigned short* __restrict__ Bt,
    const float* __restrict__ bias, float* __restrict__ C) {
  const int K = 1024;
  __shared__ unsigned short As[128 * 32];
  __shared__ unsigned short Bs[128 * 32];
  const int t = threadIdx.x;
  const int lane = t & 63, wave = t >> 6;
  const int bm0 = blockIdx.y * 128, bn0 = blockIdx.x * 128;
  const int wm = (wave >> 1) * 64, wn = (wave & 1) * 64;
  const int lr = lane & 15, q8 = (lane >> 4) * 8;
  f32x4 acc[4][4] = {};
  for (int k0 = 0; k0 < K; k0 += 32) {
#pragma unroll
    for (int it = 0; it < 2; ++it) {
      int idx = t + it * 256;
      int r = idx >> 2, cg = (idx & 3) * 8;
      *(u32x4*)(&As[r * 32 + cg]) = *(const u32x4*)(&A[(size_t)(bm0 + r) * K + k0 + cg]);
      *(u32x4*)(&Bs[r * 32 + cg]) = *(const u32x4*)(&Bt[(size_t)(bn0 + r) * K + k0 + cg]);
    }
    __syncthreads();
    bf16x8 af[4], bfr[4];
#pragma unroll
    for (int i = 0; i < 4; ++i) af[i] = *(const bf16x8*)(&As[(wm + i * 16 + lr) * 32 + q8]);
#pragma unroll
    for (int j = 0; j < 4; ++j) bfr[j] = *(const bf16x8*)(&Bs[(wn + j * 16 + lr) * 32 + q8]);
#pragma unroll
    for (int i = 0; i < 4; ++i)
#pragma unroll
      for (int j = 0; j < 4; ++j)
        acc[i][j] = MFMA16(af[i], bfr[j], acc[i][j]);
    __syncthreads();
  }
  const int lq4 = (lane >> 4) * 4;
#pragma unroll
  for (int i = 0; i < 4; ++i)
#pragma unroll
    for (int j = 0; j < 4; ++j)
#pragma unroll
      for (int r = 0; r < 4; ++r) {
        int row = bm0 + wm + i * 16 + lq4 + r;
        int col = bn0 + wn + j * 16 + lr;
        C[(size_t)row * 1024 + col] = acc[i][j][r] + bias[col];
      }
}

extern "C" void kernel_launch(void* const* d_in, const int* in_sizes, int n_in,
                              void* d_out, int out_size, void* d_ws, size_t ws_size,
                              hipStream_t stream) {
  const float* x    = (const float*)d_in[0];
  const float* mask = (const float*)d_in[1];
  const float* wqkv = (const float*)d_in[2];
  const float* wout = (const float*)d_in[3];
  const float* bout = (const float*)d_in[4];
  float* out = (float*)d_out;
  char* ws = (char*)d_ws;
  unsigned short* xbf   = (unsigned short*)(ws);                      // 8 MB  [4096][1024]
  unsigned short* wqkvt = (unsigned short*)(ws + (size_t)( 8 << 20)); // 6 MB  [3072][1024]
  unsigned short* woutt = (unsigned short*)(ws + (size_t)(14 << 20)); // 2 MB  [1024][1024]
  unsigned short* qb    = (unsigned short*)(ws + (size_t)(16 << 20)); // 8 MB  [B][H][N][DH]
  unsigned short* kb    = (unsigned short*)(ws + (size_t)(24 << 20)); // 8 MB  [B][H][N][DH]
  unsigned short* vt    = (unsigned short*)(ws + (size_t)(32 << 20)); // 8 MB  [B][H][DH][N]
  unsigned short* ao    = (unsigned short*)(ws + (size_t)(40 << 20)); // 8 MB  [4096][1024]

  k_cvt<<<2048, 256, 0, stream>>>(x, xbf, 524288);
  k_transpose_cvt<<<dim3(96, 32), 256, 0, stream>>>(wqkv, wqkvt, 1024, 3072);
  k_transpose_cvt<<<dim3(32, 32), 256, 0, stream>>>(wout, woutt, 1024, 1024);
  k_gemm_qkv<<<dim3(24, 32), 256, 0, stream>>>(xbf, wqkvt, qb, kb, vt);
  k_attn<<<1024, 256, 0, stream>>>(qb, kb, vt, mask, ao);
  k_gemm_out<<<dim3(8, 32), 256, 0, stream>>>(ao, woutt, bout, out);
}

// Round 3
// 208.381 us; speedup vs baseline: 1.7065x; 1.4115x over previous
//
#include <hip/hip_runtime.h>

#define INF __builtin_inff()

typedef __attribute__((ext_vector_type(8))) short bf16x8;
typedef __attribute__((ext_vector_type(4))) short s16x4;
typedef __attribute__((ext_vector_type(4))) float f32x4;
typedef __attribute__((ext_vector_type(8))) unsigned short u16x8;

#define MFMA16(a, b, c) __builtin_amdgcn_mfma_f32_16x16x32_bf16(a, b, c, 0, 0, 0)

// async global->LDS, 16B per lane; LDS dest = wave-uniform base + lane*16
#define ASYNC16(g, l) __builtin_amdgcn_global_load_lds( \
    (const __attribute__((address_space(1))) unsigned int*)(const void*)(g), \
    (__attribute__((address_space(3))) unsigned int*)(void*)(l), 16, 0, 0)

__device__ __forceinline__ unsigned short f2bf(float f) {
  union { float f; unsigned u; } v; v.f = f;
  unsigned r = v.u + 0x7fffu + ((v.u >> 16) & 1u);   // RNE
  return (unsigned short)(r >> 16);
}

// ---------- fp32 -> bf16 elementwise (8 elems / thread) ----------
__global__ void k_cvt(const float* __restrict__ src, unsigned short* __restrict__ dst, int n8) {
  int i = blockIdx.x * blockDim.x + threadIdx.x;
  if (i >= n8) return;
  const float4* s = (const float4*)src + (size_t)i * 2;
  float4 a = s[0], b = s[1];
  u16x8 o;
  o[0] = f2bf(a.x); o[1] = f2bf(a.y); o[2] = f2bf(a.z); o[3] = f2bf(a.w);
  o[4] = f2bf(b.x); o[5] = f2bf(b.y); o[6] = f2bf(b.z); o[7] = f2bf(b.w);
  ((u16x8*)dst)[i] = o;
}

// ---------- fp32 [R][C] -> bf16 [C][R] transpose+convert ----------
__global__ __launch_bounds__(256) void k_transpose_cvt(
    const float* __restrict__ src, unsigned short* __restrict__ dst, int R, int C) {
  __shared__ float tile[32][33];
  int bc = blockIdx.x * 32;
  int br = blockIdx.y * 32;
  int tx = threadIdx.x & 31, ty = threadIdx.x >> 5;
#pragma unroll
  for (int i = 0; i < 32; i += 8)
    tile[ty + i][tx] = src[(size_t)(br + ty + i) * C + bc + tx];
  __syncthreads();
#pragma unroll
  for (int i = 0; i < 32; i += 8)
    dst[(size_t)(bc + ty + i) * R + br + tx] = f2bf(tile[tx][ty + i]);
}

// ---------- GEMM1: qkv = x @ w_qkv, scattered into q / k / v^T ----------
__global__ __launch_bounds__(256) void k_gemm_qkv(
    const unsigned short* __restrict__ A, const unsigned short* __restrict__ Bt,
    unsigned short* __restrict__ qb, unsigned short* __restrict__ kb,
    unsigned short* __restrict__ vt) {
  const int K = 1024;
  __shared__ unsigned short As[128 * 32];
  __shared__ unsigned short Bs[128 * 32];
  const int t = threadIdx.x;
  const int lane = t & 63, wave = t >> 6;
  const int bm0 = blockIdx.y * 128, bn0 = blockIdx.x * 128;
  const int wm = (wave >> 1) * 64, wn = (wave & 1) * 64;
  const int lr = lane & 15, q8 = (lane >> 4) * 8;
  f32x4 acc[4][4] = {};
  for (int k0 = 0; k0 < K; k0 += 32) {
    __syncthreads();
#pragma unroll
    for (int it = 0; it < 2; ++it) {
      int idx = t + it * 256;
      ASYNC16(&A[(size_t)(bm0 + (idx >> 2)) * K + k0 + (idx & 3) * 8], &As[idx * 8]);
      ASYNC16(&Bt[(size_t)(bn0 + (idx >> 2)) * K + k0 + (idx & 3) * 8], &Bs[idx * 8]);
    }
    __syncthreads();
    bf16x8 af[4], bfr[4];
#pragma unroll
    for (int i = 0; i < 4; ++i) af[i] = *(const bf16x8*)(&As[(wm + i * 16 + lr) * 32 + q8]);
#pragma unroll
    for (int j = 0; j < 4; ++j) bfr[j] = *(const bf16x8*)(&Bs[(wn + j * 16 + lr) * 32 + q8]);
#pragma unroll
    for (int i = 0; i < 4; ++i)
#pragma unroll
      for (int j = 0; j < 4; ++j)
        acc[i][j] = MFMA16(af[i], bfr[j], acc[i][j]);
  }
  const int lq4 = (lane >> 4) * 4;
#pragma unroll
  for (int i = 0; i < 4; ++i) {
#pragma unroll
    for (int j = 0; j < 4; ++j) {
#pragma unroll
      for (int r = 0; r < 4; ++r) {
        int row = bm0 + wm + i * 16 + lq4 + r;   // token 0..4095
        int col = bn0 + wn + j * 16 + lr;        // 0..3071
        unsigned short v = f2bf(acc[i][j][r]);
        int b = row >> 10, n = row & 1023;
        int sec = col >> 10, js = col & 1023;
        int h = js >> 6, d = js & 63;
        size_t bh = (size_t)(b * 16 + h);
        if (sec == 0)      qb[(bh * 1024 + n) * 64 + d] = v;
        else if (sec == 1) kb[(bh * 1024 + n) * 64 + d] = v;
        else               vt[(bh * 64 + d) * 1024 + n] = v;   // V transposed [DH][N]
      }
    }
  }
}

// ---------- Flash attention v3: LDS-staged K/V (async DMA), XCD-swizzled ----------
__global__ __launch_bounds__(256, 4) void k_attn(
    const unsigned short* __restrict__ qb, const unsigned short* __restrict__ kb,
    const unsigned short* __restrict__ vt, const float* __restrict__ mask,
    unsigned short* __restrict__ ao) {
  __shared__ unsigned short Ks[64 * 64];     // [kc][d], chunk-XOR-swizzled, 8KB
  __shared__ unsigned short Vs[64 * 64];     // [d][kc], chunk-XOR-swizzled, 8KB
  __shared__ float bias[1024];               // 0 / -inf per key
  __shared__ unsigned short P[4][16 * 72];   // per-wave P tile, 144B row stride
  const int bx = blockIdx.x;
  const int bh = (bx & 7) + 8 * (bx >> 7);   // same-XCD blocks share 8 bh-groups
  const int qc = (bx >> 3) & 15;
  const int b = bh >> 4, h = bh & 15;
  const int t = threadIdx.x;
  const int wave = t >> 6, lane = t & 63;
  const int lr = lane & 15, quad = lane >> 4;
  const int q0 = qc * 64 + wave * 16;
  const unsigned short* qp = qb + ((size_t)bh << 16);
  const unsigned short* kp = kb + ((size_t)bh << 16);
  const unsigned short* vp = vt + ((size_t)bh << 16);
#pragma unroll
  for (int i = 0; i < 4; ++i) {
    int idx = t + i * 256;
    bias[idx] = (mask[b * 1024 + idx] == 0.f) ? -INF : 0.f;
  }
  unsigned short* Pw = P[wave];
  bf16x8 qv0 = *(const bf16x8*)(qp + (q0 + lr) * 64 + quad * 8);
  bf16x8 qv1 = *(const bf16x8*)(qp + (q0 + lr) * 64 + 32 + quad * 8);
  float m = -INF, l = 0.f;
  f32x4 o[4] = {};
  const int sw = lr & 7;
  for (int kc0 = 0; kc0 < 1024; kc0 += 64) {
    __syncthreads();                         // prev-iter LDS reads done (covers bias on iter 0)
#pragma unroll
    for (int it = 0; it < 2; ++it) {
      int idx = t + it * 256;                // 0..511
      int row = idx >> 3;
      int gch = (idx ^ row) & 7;             // chunk XOR swizzle
      ASYNC16(kp + (kc0 + row) * 64 + gch * 8, &Ks[idx * 8]);
      ASYNC16(vp + (size_t)row * 1024 + kc0 + gch * 8, &Vs[idx * 8]);
    }
    __syncthreads();                         // vmcnt drained -> tiles visible
    // S^T tiles = K·Q^T : C[kc][q], lane holds kc=quad*4+r, q=lr
    f32x4 st[4];
#pragma unroll
    for (int tt = 0; tt < 4; ++tt) {
      int krow = tt * 16 + lr;
      bf16x8 k0 = *(const bf16x8*)(&Ks[krow * 64 + ((quad ^ sw)) * 8]);
      bf16x8 k1 = *(const bf16x8*)(&Ks[krow * 64 + (((4 + quad) ^ sw)) * 8]);
      f32x4 c = {};
      c = MFMA16(k0, qv0, c);
      c = MFMA16(k1, qv1, c);
      st[tt] = c;
    }
    float tm = -INF;
#pragma unroll
    for (int tt = 0; tt < 4; ++tt) {
      float4 bv = *(const float4*)(&bias[kc0 + tt * 16 + quad * 4]);
      const float* bvp = (const float*)&bv;
#pragma unroll
      for (int r = 0; r < 4; ++r) {
        float v = fmaf(st[tt][r], 0.125f, bvp[r]);
        st[tt][r] = v;
        tm = fmaxf(tm, v);
      }
    }
    tm = fmaxf(tm, __shfl_xor(tm, 16));
    tm = fmaxf(tm, __shfl_xor(tm, 32));
    float mn = fmaxf(m, tm);
    bool ok = (mn != -INF);
    float alpha = ok ? __expf(m - mn) : 1.f;
    float ps = 0.f;
#pragma unroll
    for (int tt = 0; tt < 4; ++tt) {
      s16x4 pv;
#pragma unroll
      for (int r = 0; r < 4; ++r) {
        float pe = ok ? __expf(st[tt][r] - mn) : 0.f;
        ps += pe;
        pv[r] = (short)f2bf(pe);
      }
      *(s16x4*)(&Pw[lr * 72 + tt * 16 + quad * 4]) = pv;
    }
    ps += __shfl_xor(ps, 16);
    ps += __shfl_xor(ps, 32);
    l = l * alpha + ps;
    m = mn;
    float ar[4];
#pragma unroll
    for (int r = 0; r < 4; ++r) ar[r] = __shfl(alpha, quad * 4 + r);
#pragma unroll
    for (int jj = 0; jj < 4; ++jj)
#pragma unroll
      for (int r = 0; r < 4; ++r) o[jj][r] *= ar[r];
    // PV: A = P (LDS, x32 A-layout), B = V^T rows from swizzled LDS tile
#pragma unroll
    for (int sh = 0; sh < 2; ++sh) {
      bf16x8 pa = *(const bf16x8*)(&Pw[lr * 72 + sh * 32 + quad * 8]);
#pragma unroll
      for (int jj = 0; jj < 4; ++jj) {
        bf16x8 vbf = *(const bf16x8*)(&Vs[(jj * 16 + lr) * 64 + (((sh * 4 + quad) ^ sw)) * 8]);
        o[jj] = MFMA16(pa, vbf, o[jj]);
      }
    }
  }
  float inv = (m != -INF) ? 1.f / l : 0.f;
  if (bias[q0 + lr] != 0.f) inv = 0.f;       // masked q-row -> zero output row
  float ir[4];
#pragma unroll
  for (int r = 0; r < 4; ++r) ir[r] = __shfl(inv, quad * 4 + r);
  const int tok0 = b * 1024 + q0 + quad * 4;
#pragma unroll
  for (int jj = 0; jj < 4; ++jj)
#pragma unroll
    for (int r = 0; r < 4; ++r)
      ao[(size_t)(tok0 + r) * 1024 + h * 64 + jj * 16 + lr] = f2bf(o[jj][r] * ir[r]);
}

// ---------- GEMM2: out = attn_out @ w_out + b_out (fp32 out), 64x128 tiles ----------
__global__ __launch_bounds__(256) void k_gemm_out(
    const unsigned short* __restrict__ A, const unsigned short* __restrict__ Bt,
    const float* __restrict__ bias, float* __restrict__ C) {
  const int K = 1024;
  __shared__ unsigned short As[64 * 32];
  __shared__ unsigned short Bs[128 * 32];
  const int t = threadIdx.x;
  const int lane = t & 63, wave = t >> 6;
  const int bm0 = blockIdx.y * 64, bn0 = blockIdx.x * 128;
  const int wm = (wave >> 1) * 32, wn = (wave & 1) * 64;
  const int lr = lane & 15, q8 = (lane >> 4) * 8;
  f32x4 acc[2][4] = {};
  for (int k0 = 0; k0 < K; k0 += 32) {
    __syncthreads();
    ASYNC16(&A[(size_t)(bm0 + (t >> 2)) * K + k0 + (t & 3) * 8], &As[t * 8]);
#pragma unroll
    for (int it = 0; it < 2; ++it) {
      int idx = t + it * 256;
      ASYNC16(&Bt[(size_t)(bn0 + (idx >> 2)) * K + k0 + (idx & 3) * 8], &Bs[idx * 8]);
    }
    __syncthreads();
    bf16x8 af[2], bfr[4];
#pragma unroll
    for (int i = 0; i < 2; ++i) af[i] = *(const bf16x8*)(&As[(wm + i * 16 + lr) * 32 + q8]);
#pragma unroll
    for (int j = 0; j < 4; ++j) bfr[j] = *(const bf16x8*)(&Bs[(wn + j * 16 + lr) * 32 + q8]);
#pragma unroll
    for (int i = 0; i < 2; ++i)
#pragma unroll
      for (int j = 0; j < 4; ++j)
        acc[i][j] = MFMA16(af[i], bfr[j], acc[i][j]);
  }
  const int lq4 = (lane >> 4) * 4;
#pragma unroll
  for (int i = 0; i < 2; ++i)
#pragma unroll
    for (int j = 0; j < 4; ++j)
#pragma unroll
      for (int r = 0; r < 4; ++r) {
        int row = bm0 + wm + i * 16 + lq4 + r;
        int col = bn0 + wn + j * 16 + lr;
        C[(size_t)row * 1024 + col] = acc[i][j][r] + bias[col];
      }
}

extern "C" void kernel_launch(void* const* d_in, const int* in_sizes, int n_in,
                              void* d_out, int out_size, void* d_ws, size_t ws_size,
                              hipStream_t stream) {
  const float* x    = (const float*)d_in[0];
  const float* mask = (const float*)d_in[1];
  const float* wqkv = (const float*)d_in[2];
  const float* wout = (const float*)d_in[3];
  const float* bout = (const float*)d_in[4];
  float* out = (float*)d_out;
  char* ws = (char*)d_ws;
  unsigned short* xbf   = (unsigned short*)(ws);                      // 8 MB  [4096][1024]
  unsigned short* wqkvt = (unsigned short*)(ws + (size_t)( 8 << 20)); // 6 MB  [3072][1024]
  unsigned short* woutt = (unsigned short*)(ws + (size_t)(14 << 20)); // 2 MB  [1024][1024]
  unsigned short* qb    = (unsigned short*)(ws + (size_t)(16 << 20)); // 8 MB  [B][H][N][DH]
  unsigned short* kb    = (unsigned short*)(ws + (size_t)(24 << 20)); // 8 MB  [B][H][N][DH]
  unsigned short* vt    = (unsigned short*)(ws + (size_t)(32 << 20)); // 8 MB  [B][H][DH][N]
  unsigned short* ao    = (unsigned short*)(ws + (size_t)(40 << 20)); // 8 MB  [4096][1024]

  k_cvt<<<2048, 256, 0, stream>>>(x, xbf, 524288);
  k_transpose_cvt<<<dim3(96, 32), 256, 0, stream>>>(wqkv, wqkvt, 1024, 3072);
  k_transpose_cvt<<<dim3(32, 32), 256, 0, stream>>>(wout, woutt, 1024, 1024);
  k_gemm_qkv<<<dim3(24, 32), 256, 0, stream>>>(xbf, wqkvt, qb, kb, vt);
  k_attn<<<1024, 256, 0, stream>>>(qb, kb, vt, mask, ao);
  k_gemm_out<<<dim3(8, 64), 256, 0, stream>>>(ao, woutt, bout, out);
}

// Round 4
// 196.254 us; speedup vs baseline: 1.8120x; 1.0618x over previous
//
#include <hip/hip_runtime.h>

#define INF __builtin_inff()

typedef __attribute__((ext_vector_type(8))) short bf16x8;
typedef __attribute__((ext_vector_type(4))) short s16x4;
typedef __attribute__((ext_vector_type(4))) float f32x4;
typedef __attribute__((ext_vector_type(8))) unsigned short u16x8;

#define MFMA16(a, b, c) __builtin_amdgcn_mfma_f32_16x16x32_bf16(a, b, c, 0, 0, 0)

// async global->LDS, 16B per lane; LDS dest = wave-uniform base + lane*16
#define ASYNC16(g, l) __builtin_amdgcn_global_load_lds( \
    (const __attribute__((address_space(1))) unsigned int*)(const void*)(g), \
    (__attribute__((address_space(3))) unsigned int*)(void*)(l), 16, 0, 0)

__device__ __forceinline__ unsigned short f2bf(float f) {
  union { float f; unsigned u; } v; v.f = f;
  unsigned r = v.u + 0x7fffu + ((v.u >> 16) & 1u);   // RNE
  return (unsigned short)(r >> 16);
}

// ---------- mask scan: pos[b][n] (dest slot / 0xFFFF), perm[b][slot]=n, nv[b] ----------
__global__ __launch_bounds__(1024) void k_scan(
    const float* __restrict__ mask, unsigned short* __restrict__ pos,
    unsigned short* __restrict__ perm, int* __restrict__ nv) {
  __shared__ int wsum[16];
  __shared__ int woff[16];
  const int b = blockIdx.x, t = threadIdx.x;
  const int wid = t >> 6, lane = t & 63;
  const bool valid = (mask[b * 1024 + t] != 0.f);
  unsigned long long bal = __ballot(valid);
  int pre = __popcll(bal & ((1ull << lane) - 1ull));
  if (lane == 0) wsum[wid] = __popcll(bal);
  __syncthreads();
  if (t < 16) { int s = 0; for (int i = 0; i < t; ++i) s += wsum[i]; woff[t] = s; }
  __syncthreads();
  int p = woff[wid] + pre;
  pos[b * 1024 + t] = valid ? (unsigned short)p : (unsigned short)0xFFFF;
  if (valid) perm[b * 1024 + p] = (unsigned short)t;
  if (t == 1023) nv[b] = woff[15] + wsum[15];
}

// ---------- fp32 -> bf16 elementwise (8 elems / thread) ----------
__global__ void k_cvt(const float* __restrict__ src, unsigned short* __restrict__ dst, int n8) {
  int i = blockIdx.x * blockDim.x + threadIdx.x;
  if (i >= n8) return;
  const float4* s = (const float4*)src + (size_t)i * 2;
  float4 a = s[0], b = s[1];
  u16x8 o;
  o[0] = f2bf(a.x); o[1] = f2bf(a.y); o[2] = f2bf(a.z); o[3] = f2bf(a.w);
  o[4] = f2bf(b.x); o[5] = f2bf(b.y); o[6] = f2bf(b.z); o[7] = f2bf(b.w);
  ((u16x8*)dst)[i] = o;
}

// ---------- fp32 [R][C] -> bf16 [C][R] transpose+convert ----------
__global__ __launch_bounds__(256) void k_transpose_cvt(
    const float* __restrict__ src, unsigned short* __restrict__ dst, int R, int C) {
  __shared__ float tile[32][33];
  int bc = blockIdx.x * 32;
  int br = blockIdx.y * 32;
  int tx = threadIdx.x & 31, ty = threadIdx.x >> 5;
#pragma unroll
  for (int i = 0; i < 32; i += 8)
    tile[ty + i][tx] = src[(size_t)(br + ty + i) * C + bc + tx];
  __syncthreads();
#pragma unroll
  for (int i = 0; i < 32; i += 8)
    dst[(size_t)(bc + ty + i) * R + br + tx] = f2bf(tile[tx][ty + i]);
}

// ---------- GEMM1: qkv = x @ w_qkv; compacted rows via pos; coalesced epilogue ----------
__global__ __launch_bounds__(256) void k_gemm_qkv(
    const unsigned short* __restrict__ A, const unsigned short* __restrict__ Bt,
    const unsigned short* __restrict__ pos,
    unsigned short* __restrict__ qcmp, unsigned short* __restrict__ kcmp,
    unsigned short* __restrict__ vcmp) {
  const int K = 1024;
  __shared__ unsigned short SH[64 * 136];     // 17408 B: As(4096)|Bs(4096) then Ep[64][136]
  unsigned short* As = SH;
  unsigned short* Bs = SH + 4096;
  const int t = threadIdx.x;
  const int lane = t & 63, wave = t >> 6;
  const int bm0 = blockIdx.y * 128, bn0 = blockIdx.x * 128;
  const int wm = (wave >> 1) * 64, wn = (wave & 1) * 64;
  const int lr = lane & 15, q8 = (lane >> 4) * 8, quad = lane >> 4;
  f32x4 acc[4][4] = {};
  for (int k0 = 0; k0 < K; k0 += 32) {
    __syncthreads();
#pragma unroll
    for (int it = 0; it < 2; ++it) {
      int idx = t + it * 256;
      ASYNC16(&A[(size_t)(bm0 + (idx >> 2)) * K + k0 + (idx & 3) * 8], &As[idx * 8]);
      ASYNC16(&Bt[(size_t)(bn0 + (idx >> 2)) * K + k0 + (idx & 3) * 8], &Bs[idx * 8]);
    }
    __syncthreads();
    bf16x8 af[4], bfr[4];
#pragma unroll
    for (int i = 0; i < 4; ++i) af[i] = *(const bf16x8*)(&As[(wm + i * 16 + lr) * 32 + q8]);
#pragma unroll
    for (int j = 0; j < 4; ++j) bfr[j] = *(const bf16x8*)(&Bs[(wn + j * 16 + lr) * 32 + q8]);
#pragma unroll
    for (int i = 0; i < 4; ++i)
#pragma unroll
      for (int j = 0; j < 4; ++j)
        acc[i][j] = MFMA16(af[i], bfr[j], acc[i][j]);
  }
  // epilogue: LDS repack (two 64-row halves), compacted coalesced u16x8 stores
  const int b = bm0 >> 10;
  const int sec = bn0 >> 10;                  // 0=Q 1=K 2=V (uniform per block)
  unsigned short* dstT = (sec == 0) ? qcmp : (sec == 1) ? kcmp : vcmp;
  const int js0 = bn0 & 1023;
#pragma unroll
  for (int hh = 0; hh < 2; ++hh) {
    __syncthreads();
    if ((wave >> 1) == hh) {
#pragma unroll
      for (int i = 0; i < 4; ++i)
#pragma unroll
        for (int j = 0; j < 4; ++j)
#pragma unroll
          for (int r = 0; r < 4; ++r)
            SH[(i * 16 + quad * 4 + r) * 136 + wn + j * 16 + lr] = f2bf(acc[i][j][r]);
    }
    __syncthreads();
#pragma unroll
    for (int rr = 0; rr < 4; ++rr) {
      int lrow = (t >> 4) + rr * 16;          // 0..63
      int ck = t & 15;
      int tok = (bm0 & 1023) + hh * 64 + lrow;
      int dr = pos[b * 1024 + tok];
      if (dr != 0xFFFF) {
        int js = js0 + ck * 8;
        int h = js >> 6, d = js & 63;
        u16x8 v = *(u16x8*)(&SH[lrow * 136 + ck * 8]);
        *(u16x8*)(&dstT[(((size_t)(b * 16 + h)) * 1024 + dr) * 64 + d]) = v;
      }
    }
  }
}

// ---------- transpose compacted V: [bh][slot][d] -> [bh][d][slot], zero-pad tile ----------
__global__ __launch_bounds__(256) void k_vtrans(
    const unsigned short* __restrict__ vc, unsigned short* __restrict__ vt,
    const int* __restrict__ nvb) {
  __shared__ unsigned short tile[32][33];
  const int bh = blockIdx.z;
  const int s0 = blockIdx.y * 32;
  const int d0 = blockIdx.x * 32;
  const int nv = nvb[bh >> 4];
  if (s0 >= ((nv + 63) & ~63)) return;        // beyond last read tile (uniform)
  const int tx = threadIdx.x & 31, ty = threadIdx.x >> 5;
  const unsigned short* src = vc + ((size_t)bh << 16);
  unsigned short* dst = vt + ((size_t)bh << 16);
#pragma unroll
  for (int i = 0; i < 32; i += 8)
    tile[ty + i][tx] = src[(size_t)(s0 + ty + i) * 64 + d0 + tx];
  __syncthreads();
#pragma unroll
  for (int i = 0; i < 32; i += 8) {
    int slot = s0 + tx;
    dst[(size_t)(d0 + ty + i) * 1024 + slot] = (slot < nv) ? tile[tx][ty + i] : (unsigned short)0;
  }
}

// ---------- Flash attention over compacted tokens ----------
__global__ __launch_bounds__(256, 4) void k_attn(
    const unsigned short* __restrict__ qcmp, const unsigned short* __restrict__ kcmp,
    const unsigned short* __restrict__ vtc, const unsigned short* __restrict__ perm,
    const int* __restrict__ nvb, unsigned short* __restrict__ ao) {
  __shared__ unsigned short Ks[64 * 64];
  __shared__ unsigned short Vs[64 * 64];
  __shared__ unsigned short P[4][16 * 72];
  const int bx = blockIdx.x;
  const int bh = (bx & 7) + 8 * (bx >> 7);   // XCD-local bh grouping
  const int qcb = (bx >> 3) & 15;
  const int b = bh >> 4, h = bh & 15;
  const int nv = nvb[b];
  if (qcb * 64 >= nv) return;                // whole block idle (uniform)
  const int t = threadIdx.x;
  const int wave = t >> 6, lane = t & 63;
  const int lr = lane & 15, quad = lane >> 4;
  const int q0 = qcb * 64 + wave * 16;
  const unsigned short* qp = qcmp + ((size_t)bh << 16);
  const unsigned short* kp = kcmp + ((size_t)bh << 16);
  const unsigned short* vp = vtc + ((size_t)bh << 16);
  unsigned short* Pw = P[wave];
  bf16x8 qv0 = *(const bf16x8*)(qp + (q0 + lr) * 64 + quad * 8);
  bf16x8 qv1 = *(const bf16x8*)(qp + (q0 + lr) * 64 + 32 + quad * 8);
  float m = -INF, l = 0.f;
  f32x4 o[4] = {};
  const int sw = lr & 7;
  const int nk = (nv + 63) >> 6;
  for (int it = 0; it < nk; ++it) {
    const int kc0 = it * 64;
    __syncthreads();                         // prev-iter LDS reads done
#pragma unroll
    for (int ld = 0; ld < 2; ++ld) {
      int idx = t + ld * 256;                // 0..511
      int row = idx >> 3;
      int gch = (idx ^ row) & 7;             // chunk XOR swizzle
      ASYNC16(kp + (kc0 + row) * 64 + gch * 8, &Ks[idx * 8]);
      ASYNC16(vp + (size_t)row * 1024 + kc0 + gch * 8, &Vs[idx * 8]);
    }
    __syncthreads();                         // tiles visible
    f32x4 st[4];
#pragma unroll
    for (int tt = 0; tt < 4; ++tt) {
      int krow = tt * 16 + lr;
      bf16x8 k0 = *(const bf16x8*)(&Ks[krow * 64 + ((quad ^ sw)) * 8]);
      bf16x8 k1 = *(const bf16x8*)(&Ks[krow * 64 + (((4 + quad) ^ sw)) * 8]);
      f32x4 c = {};
      c = MFMA16(k0, qv0, c);
      c = MFMA16(k1, qv1, c);
      st[tt] = c;
    }
    float tm = -INF;
#pragma unroll
    for (int tt = 0; tt < 4; ++tt) {
#pragma unroll
      for (int r = 0; r < 4; ++r) {
        int slot = kc0 + tt * 16 + quad * 4 + r;
        float v = (slot < nv) ? st[tt][r] * 0.125f : -INF;
        st[tt][r] = v;
        tm = fmaxf(tm, v);
      }
    }
    tm = fmaxf(tm, __shfl_xor(tm, 16));
    tm = fmaxf(tm, __shfl_xor(tm, 32));
    float mn = fmaxf(m, tm);
    float alpha = __expf(m - mn);            // m=-INF only on first tile: exp(-inf)=0, l=0 anyway
    if (m == -INF) alpha = 1.f;
    float ps = 0.f;
#pragma unroll
    for (int tt = 0; tt < 4; ++tt) {
      s16x4 pv;
#pragma unroll
      for (int r = 0; r < 4; ++r) {
        float pe = __expf(st[tt][r] - mn);   // -inf slots -> 0
        ps += pe;
        pv[r] = (short)f2bf(pe);
      }
      *(s16x4*)(&Pw[lr * 72 + tt * 16 + quad * 4]) = pv;
    }
    ps += __shfl_xor(ps, 16);
    ps += __shfl_xor(ps, 32);
    l = l * alpha + ps;
    m = mn;
    float ar[4];
#pragma unroll
    for (int r = 0; r < 4; ++r) ar[r] = __shfl(alpha, quad * 4 + r);
#pragma unroll
    for (int jj = 0; jj < 4; ++jj)
#pragma unroll
      for (int r = 0; r < 4; ++r) o[jj][r] *= ar[r];
#pragma unroll
    for (int sh = 0; sh < 2; ++sh) {
      bf16x8 pa = *(const bf16x8*)(&Pw[lr * 72 + sh * 32 + quad * 8]);
#pragma unroll
      for (int jj = 0; jj < 4; ++jj) {
        bf16x8 vbf = *(const bf16x8*)(&Vs[(jj * 16 + lr) * 64 + (((sh * 4 + quad) ^ sw)) * 8]);
        o[jj] = MFMA16(pa, vbf, o[jj]);
      }
    }
  }
  float inv = 1.f / l;                       // all compacted rows valid; l>0
  float ir[4];
#pragma unroll
  for (int r = 0; r < 4; ++r) ir[r] = __shfl(inv, quad * 4 + r);
#pragma unroll
  for (int r = 0; r < 4; ++r) {
    int slot = q0 + quad * 4 + r;
    if (slot < nv) {
      int tok = perm[b * 1024 + slot];
      size_t rowb = ((size_t)(b * 1024 + tok)) * 1024 + h * 64;
#pragma unroll
      for (int jj = 0; jj < 4; ++jj)
        ao[rowb + jj * 16 + lr] = f2bf(o[jj][r] * ir[r]);
    }
  }
}

// ---------- GEMM2: out = attn_out @ w_out + b_out (fp32 out), 64x128 tiles ----------
__global__ __launch_bounds__(256) void k_gemm_out(
    const unsigned short* __restrict__ A, const unsigned short* __restrict__ Bt,
    const float* __restrict__ bias, float* __restrict__ C) {
  const int K = 1024;
  __shared__ unsigned short As[64 * 32];
  __shared__ unsigned short Bs[128 * 32];
  const int t = threadIdx.x;
  const int lane = t & 63, wave = t >> 6;
  const int bm0 = blockIdx.y * 64, bn0 = blockIdx.x * 128;
  const int wm = (wave >> 1) * 32, wn = (wave & 1) * 64;
  const int lr = lane & 15, q8 = (lane >> 4) * 8;
  f32x4 acc[2][4] = {};
  for (int k0 = 0; k0 < K; k0 += 32) {
    __syncthreads();
    ASYNC16(&A[(size_t)(bm0 + (t >> 2)) * K + k0 + (t & 3) * 8], &As[t * 8]);
#pragma unroll
    for (int it = 0; it < 2; ++it) {
      int idx = t + it * 256;
      ASYNC16(&Bt[(size_t)(bn0 + (idx >> 2)) * K + k0 + (idx & 3) * 8], &Bs[idx * 8]);
    }
    __syncthreads();
    bf16x8 af[2], bfr[4];
#pragma unroll
    for (int i = 0; i < 2; ++i) af[i] = *(const bf16x8*)(&As[(wm + i * 16 + lr) * 32 + q8]);
#pragma unroll
    for (int j = 0; j < 4; ++j) bfr[j] = *(const bf16x8*)(&Bs[(wn + j * 16 + lr) * 32 + q8]);
#pragma unroll
    for (int i = 0; i < 2; ++i)
#pragma unroll
      for (int j = 0; j < 4; ++j)
        acc[i][j] = MFMA16(af[i], bfr[j], acc[i][j]);
  }
  const int lq4 = (lane >> 4) * 4;
#pragma unroll
  for (int i = 0; i < 2; ++i)
#pragma unroll
    for (int j = 0; j < 4; ++j)
#pragma unroll
      for (int r = 0; r < 4; ++r) {
        int row = bm0 + wm + i * 16 + lq4 + r;
        int col = bn0 + wn + j * 16 + lr;
        C[(size_t)row * 1024 + col] = acc[i][j][r] + bias[col];
      }
}

extern "C" void kernel_launch(void* const* d_in, const int* in_sizes, int n_in,
                              void* d_out, int out_size, void* d_ws, size_t ws_size,
                              hipStream_t stream) {
  const float* x    = (const float*)d_in[0];
  const float* mask = (const float*)d_in[1];
  const float* wqkv = (const float*)d_in[2];
  const float* wout = (const float*)d_in[3];
  const float* bout = (const float*)d_in[4];
  float* out = (float*)d_out;
  char* ws = (char*)d_ws;
  // layout (48 MB + 33 KB, with aliasing):
  unsigned short* xbf   = (unsigned short*)(ws);                      // [0,8)   x bf16 (dead after gemm1)
  unsigned short* vtc   = (unsigned short*)(ws);                      //         alias: V^T compacted (vtrans->attn)
  unsigned short* wqkvt = (unsigned short*)(ws + (size_t)( 8 << 20)); // [8,14)
  unsigned short* woutt = (unsigned short*)(ws + (size_t)(14 << 20)); // [14,16)
  unsigned short* qcmp  = (unsigned short*)(ws + (size_t)(16 << 20)); // [16,24)
  unsigned short* kcmp  = (unsigned short*)(ws + (size_t)(24 << 20)); // [24,32)
  unsigned short* vcmp  = (unsigned short*)(ws + (size_t)(32 << 20)); // [32,40)  (dead after vtrans)
  unsigned short* ao    = (unsigned short*)(ws + (size_t)(32 << 20)); //          alias: attn out (attn->gemm2)
  unsigned short* pos   = (unsigned short*)(ws + (size_t)(40 << 20)); // 8 KB
  unsigned short* perm  = (unsigned short*)(ws + (size_t)(40 << 20) + 8192);   // 8 KB
  int*            nvb   = (int*)           (ws + (size_t)(40 << 20) + 16384);  // 16 B

  k_scan<<<4, 1024, 0, stream>>>(mask, pos, perm, nvb);
  k_cvt<<<2048, 256, 0, stream>>>(x, xbf, 524288);
  k_transpose_cvt<<<dim3(96, 32), 256, 0, stream>>>(wqkv, wqkvt, 1024, 3072);
  k_transpose_cvt<<<dim3(32, 32), 256, 0, stream>>>(wout, woutt, 1024, 1024);
  k_gemm_qkv<<<dim3(24, 32), 256, 0, stream>>>(xbf, wqkvt, pos, qcmp, kcmp, vcmp);
  k_vtrans<<<dim3(2, 32, 64), 256, 0, stream>>>(vcmp, vtc, nvb);
  hipMemsetAsync(ao, 0, (size_t)8 << 20, stream);
  k_attn<<<1024, 256, 0, stream>>>(qcmp, kcmp, vtc, perm, nvb, ao);
  k_gemm_out<<<dim3(8, 64), 256, 0, stream>>>(ao, woutt, bout, out);
}

// Round 5
// 164.958 us; speedup vs baseline: 2.1558x; 1.1897x over previous
//
#include <hip/hip_runtime.h>

#define INF __builtin_inff()

typedef __attribute__((ext_vector_type(8))) short bf16x8;
typedef __attribute__((ext_vector_type(4))) short s16x4;
typedef __attribute__((ext_vector_type(4))) float f32x4;
typedef __attribute__((ext_vector_type(8))) unsigned short u16x8;
typedef __attribute__((ext_vector_type(4))) unsigned short u16x4;

#define MFMA16(a, b, c) __builtin_amdgcn_mfma_f32_16x16x32_bf16(a, b, c, 0, 0, 0)

// async global->LDS, 16B per lane; LDS dest = wave-uniform base + lane*16
#define ASYNC16(g, l) __builtin_amdgcn_global_load_lds( \
    (const __attribute__((address_space(1))) unsigned int*)(const void*)(g), \
    (__attribute__((address_space(3))) unsigned int*)(void*)(l), 16, 0, 0)

__device__ __forceinline__ unsigned short f2bf(float f) {
  union { float f; unsigned u; } v; v.f = f;
  unsigned r = v.u + 0x7fffu + ((v.u >> 16) & 1u);   // RNE
  return (unsigned short)(r >> 16);
}

// ---------- mask scan: pos (unused downstream but cheap), perm[b][slot]=n, nv[b] ----------
__global__ __launch_bounds__(1024) void k_scan(
    const float* __restrict__ mask, unsigned short* __restrict__ perm, int* __restrict__ nv) {
  __shared__ int wsum[16];
  __shared__ int woff[16];
  const int b = blockIdx.x, t = threadIdx.x;
  const int wid = t >> 6, lane = t & 63;
  const bool valid = (mask[b * 1024 + t] != 0.f);
  unsigned long long bal = __ballot(valid);
  int pre = __popcll(bal & ((1ull << lane) - 1ull));
  if (lane == 0) wsum[wid] = __popcll(bal);
  __syncthreads();
  if (t < 16) { int s = 0; for (int i = 0; i < t; ++i) s += wsum[i]; woff[t] = s; }
  __syncthreads();
  int p = woff[wid] + pre;
  if (valid) perm[b * 1024 + p] = (unsigned short)t;
  if (t == 1023) nv[b] = woff[15] + wsum[15];
}

// ---------- gather-convert x rows into compacted xc (zero-pad to ceil128) ----------
__global__ __launch_bounds__(256) void k_cvtg(
    const float* __restrict__ x, const unsigned short* __restrict__ perm,
    const int* __restrict__ nvb, unsigned short* __restrict__ xc) {
  const int id = blockIdx.x;
  const int b = id >> 10, slot = id & 1023;
  const int nv = nvb[b];
  const int ce = (nv + 127) & ~127;
  if (slot >= ce) return;
  const int t = threadIdx.x;
  u16x4 o;
  if (slot < nv) {
    int tok = perm[b * 1024 + slot];
    float4 f = ((const float4*)(x + ((size_t)(b * 1024 + tok)) * 1024))[t];
    o[0] = f2bf(f.x); o[1] = f2bf(f.y); o[2] = f2bf(f.z); o[3] = f2bf(f.w);
  } else {
    o[0] = o[1] = o[2] = o[3] = 0;
  }
  ((u16x4*)(xc + ((size_t)(b * 1024 + slot)) * 1024))[t] = o;
}

// ---------- fp32 [R][C] -> bf16 [C][R] transpose+convert ----------
__global__ __launch_bounds__(256) void k_transpose_cvt(
    const float* __restrict__ src, unsigned short* __restrict__ dst, int R, int C) {
  __shared__ float tile[32][33];
  int bc = blockIdx.x * 32;
  int br = blockIdx.y * 32;
  int tx = threadIdx.x & 31, ty = threadIdx.x >> 5;
#pragma unroll
  for (int i = 0; i < 32; i += 8)
    tile[ty + i][tx] = src[(size_t)(br + ty + i) * C + bc + tx];
  __syncthreads();
#pragma unroll
  for (int i = 0; i < 32; i += 8)
    dst[(size_t)(bc + ty + i) * R + br + tx] = f2bf(tile[tx][ty + i]);
}

// ---------- GEMM1 on compacted rows: qkv = xc @ w_qkv -> qcmp/kcmp/vcmp ----------
// 1D grid 768; XCD-affine: xcd owns cols [3*xcd, 3*xcd+3); BK=64 XOR-swizzled staging.
__global__ __launch_bounds__(256) void k_gemm_qkv(
    const unsigned short* __restrict__ A, const unsigned short* __restrict__ Bt,
    const int* __restrict__ nvb,
    unsigned short* __restrict__ qcmp, unsigned short* __restrict__ kcmp,
    unsigned short* __restrict__ vcmp) {
  __shared__ unsigned short SH[16384];        // 32 KB: As[128][64] | Bs[128][64]; epilogue reuse
  unsigned short* As = SH;
  unsigned short* Bs = SH + 8192;
  const int lid = blockIdx.x;
  const int xcd = lid & 7, i6 = lid >> 3;     // i6: 0..95
  const int colt = xcd * 3 + (i6 % 3);        // 0..23
  const int rowt = i6 / 3;                    // 0..31
  const int b = rowt >> 3, mt = rowt & 7;
  const int nv = nvb[b];
  if (mt * 128 >= nv) return;
  const int bm0 = mt * 128;                   // slot base
  const int bn0 = colt * 128;
  const size_t abase = ((size_t)(b * 1024 + bm0)) * 1024;
  const int t = threadIdx.x;
  const int lane = t & 63, wave = t >> 6;
  const int wm = (wave >> 1) * 64, wn = (wave & 1) * 64;
  const int lr = lane & 15, quad = lane >> 4;
  const int sw = lr & 7;
  f32x4 acc[4][4] = {};
  for (int k0 = 0; k0 < 1024; k0 += 64) {
    __syncthreads();
#pragma unroll
    for (int j = 0; j < 4; ++j) {
      int idx = t + j * 256;                  // 0..1023
      int row = idx >> 3;
      int g = (idx ^ row) & 7;                // chunk XOR swizzle
      ASYNC16(&A[abase + (size_t)row * 1024 + k0 + g * 8], &As[idx * 8]);
      ASYNC16(&Bt[((size_t)(bn0 + row)) * 1024 + k0 + g * 8], &Bs[idx * 8]);
    }
    __syncthreads();
#pragma unroll
    for (int ks = 0; ks < 2; ++ks) {
      bf16x8 af[4], bfr[4];
#pragma unroll
      for (int i = 0; i < 4; ++i)
        af[i] = *(const bf16x8*)(&As[(wm + i * 16 + lr) * 64 + (((ks * 4 + quad) ^ sw)) * 8]);
#pragma unroll
      for (int j = 0; j < 4; ++j)
        bfr[j] = *(const bf16x8*)(&Bs[(wn + j * 16 + lr) * 64 + (((ks * 4 + quad) ^ sw)) * 8]);
#pragma unroll
      for (int i = 0; i < 4; ++i)
#pragma unroll
        for (int j = 0; j < 4; ++j)
          acc[i][j] = MFMA16(af[i], bfr[j], acc[i][j]);
    }
  }
  // epilogue: LDS repack (two 64-row halves), coalesced u16x8 stores, rows already = slots
  const int sec = bn0 >> 10;                  // 0=Q 1=K 2=V (uniform)
  unsigned short* dstT = (sec == 0) ? qcmp : (sec == 1) ? kcmp : vcmp;
  const int js0 = bn0 & 1023;
#pragma unroll
  for (int hh = 0; hh < 2; ++hh) {
    __syncthreads();
    if ((wave >> 1) == hh) {
#pragma unroll
      for (int i = 0; i < 4; ++i)
#pragma unroll
        for (int j = 0; j < 4; ++j)
#pragma unroll
          for (int r = 0; r < 4; ++r)
            SH[(i * 16 + quad * 4 + r) * 136 + wn + j * 16 + lr] = f2bf(acc[i][j][r]);
    }
    __syncthreads();
#pragma unroll
    for (int rr = 0; rr < 4; ++rr) {
      int lrow = (t >> 4) + rr * 16;          // 0..63
      int ck = t & 15;
      int slot = bm0 + hh * 64 + lrow;
      int js = js0 + ck * 8;
      int h = js >> 6, d = js & 63;
      u16x8 v = *(u16x8*)(&SH[lrow * 136 + ck * 8]);
      *(u16x8*)(&dstT[(((size_t)(b * 16 + h)) * 1024 + slot) * 64 + d]) = v;
    }
  }
}

// ---------- transpose compacted V: [bh][slot][d] -> [bh][d][slot], zero-pad tile ----------
__global__ __launch_bounds__(256) void k_vtrans(
    const unsigned short* __restrict__ vc, unsigned short* __restrict__ vt,
    const int* __restrict__ nvb) {
  __shared__ unsigned short tile[32][33];
  const int bh = blockIdx.z;
  const int s0 = blockIdx.y * 32;
  const int d0 = blockIdx.x * 32;
  const int nv = nvb[bh >> 4];
  if (s0 >= ((nv + 63) & ~63)) return;
  const int tx = threadIdx.x & 31, ty = threadIdx.x >> 5;
  const unsigned short* src = vc + ((size_t)bh << 16);
  unsigned short* dst = vt + ((size_t)bh << 16);
#pragma unroll
  for (int i = 0; i < 32; i += 8)
    tile[ty + i][tx] = src[(size_t)(s0 + ty + i) * 64 + d0 + tx];
  __syncthreads();
#pragma unroll
  for (int i = 0; i < 32; i += 8) {
    int slot = s0 + tx;
    dst[(size_t)(d0 + ty + i) * 1024 + slot] = (slot < nv) ? tile[tx][ty + i] : (unsigned short)0;
  }
}

// ---------- zero aoc pad rows [nv, ceil64(nv)) ----------
__global__ __launch_bounds__(256) void k_padzero(
    unsigned short* __restrict__ aoc, const int* __restrict__ nvb) {
  const int b = blockIdx.x;
  const int nv = nvb[b];
  const int ce = (nv + 63) & ~63;
  for (int r = nv; r < ce; ++r)
    ((unsigned long long*)(aoc + ((size_t)(b * 1024 + r)) * 1024))[threadIdx.x] = 0ull;
}

// ---------- Flash attention over compacted tokens; writes compact aoc ----------
__global__ __launch_bounds__(256, 4) void k_attn(
    const unsigned short* __restrict__ qcmp, const unsigned short* __restrict__ kcmp,
    const unsigned short* __restrict__ vtc, const int* __restrict__ nvb,
    unsigned short* __restrict__ aoc) {
  __shared__ unsigned short Ks[64 * 64];
  __shared__ unsigned short Vs[64 * 64];
  __shared__ unsigned short P[4][16 * 72];
  const int bx = blockIdx.x;
  const int bh = (bx & 7) + 8 * (bx >> 7);   // XCD-local bh grouping
  const int qcb = (bx >> 3) & 15;
  const int b = bh >> 4, h = bh & 15;
  const int nv = nvb[b];
  if (qcb * 64 >= nv) return;
  const int t = threadIdx.x;
  const int wave = t >> 6, lane = t & 63;
  const int lr = lane & 15, quad = lane >> 4;
  const int q0 = qcb * 64 + wave * 16;
  const unsigned short* qp = qcmp + ((size_t)bh << 16);
  const unsigned short* kp = kcmp + ((size_t)bh << 16);
  const unsigned short* vp = vtc + ((size_t)bh << 16);
  unsigned short* Pw = P[wave];
  bf16x8 qv0 = *(const bf16x8*)(qp + (q0 + lr) * 64 + quad * 8);
  bf16x8 qv1 = *(const bf16x8*)(qp + (q0 + lr) * 64 + 32 + quad * 8);
  float m = -INF, l = 0.f;
  f32x4 o[4] = {};
  const int sw = lr & 7;
  const int nk = (nv + 63) >> 6;
  for (int it = 0; it < nk; ++it) {
    const int kc0 = it * 64;
    __syncthreads();
#pragma unroll
    for (int ld = 0; ld < 2; ++ld) {
      int idx = t + ld * 256;
      int row = idx >> 3;
      int gch = (idx ^ row) & 7;
      ASYNC16(kp + (kc0 + row) * 64 + gch * 8, &Ks[idx * 8]);
      ASYNC16(vp + (size_t)row * 1024 + kc0 + gch * 8, &Vs[idx * 8]);
    }
    __syncthreads();
    f32x4 st[4];
#pragma unroll
    for (int tt = 0; tt < 4; ++tt) {
      int krow = tt * 16 + lr;
      bf16x8 k0 = *(const bf16x8*)(&Ks[krow * 64 + ((quad ^ sw)) * 8]);
      bf16x8 k1 = *(const bf16x8*)(&Ks[krow * 64 + (((4 + quad) ^ sw)) * 8]);
      f32x4 c = {};
      c = MFMA16(k0, qv0, c);
      c = MFMA16(k1, qv1, c);
      st[tt] = c;
    }
    float tm = -INF;
#pragma unroll
    for (int tt = 0; tt < 4; ++tt) {
#pragma unroll
      for (int r = 0; r < 4; ++r) {
        int slot = kc0 + tt * 16 + quad * 4 + r;
        float v = (slot < nv) ? st[tt][r] * 0.125f : -INF;
        st[tt][r] = v;
        tm = fmaxf(tm, v);
      }
    }
    tm = fmaxf(tm, __shfl_xor(tm, 16));
    tm = fmaxf(tm, __shfl_xor(tm, 32));
    float mn = fmaxf(m, tm);
    float alpha = __expf(m - mn);
    if (m == -INF) alpha = 1.f;
    float ps = 0.f;
#pragma unroll
    for (int tt = 0; tt < 4; ++tt) {
      s16x4 pv;
#pragma unroll
      for (int r = 0; r < 4; ++r) {
        float pe = __expf(st[tt][r] - mn);
        ps += pe;
        pv[r] = (short)f2bf(pe);
      }
      *(s16x4*)(&Pw[lr * 72 + tt * 16 + quad * 4]) = pv;
    }
    ps += __shfl_xor(ps, 16);
    ps += __shfl_xor(ps, 32);
    l = l * alpha + ps;
    m = mn;
    float ar[4];
#pragma unroll
    for (int r = 0; r < 4; ++r) ar[r] = __shfl(alpha, quad * 4 + r);
#pragma unroll
    for (int jj = 0; jj < 4; ++jj)
#pragma unroll
      for (int r = 0; r < 4; ++r) o[jj][r] *= ar[r];
#pragma unroll
    for (int sh = 0; sh < 2; ++sh) {
      bf16x8 pa = *(const bf16x8*)(&Pw[lr * 72 + sh * 32 + quad * 8]);
#pragma unroll
      for (int jj = 0; jj < 4; ++jj) {
        bf16x8 vbf = *(const bf16x8*)(&Vs[(jj * 16 + lr) * 64 + (((sh * 4 + quad) ^ sw)) * 8]);
        o[jj] = MFMA16(pa, vbf, o[jj]);
      }
    }
  }
  float inv = 1.f / l;
  float ir[4];
#pragma unroll
  for (int r = 0; r < 4; ++r) ir[r] = __shfl(inv, quad * 4 + r);
#pragma unroll
  for (int r = 0; r < 4; ++r) {
    int slot = q0 + quad * 4 + r;
    if (slot < nv) {
      size_t rowb = ((size_t)(b * 1024 + slot)) * 1024 + h * 64;
#pragma unroll
      for (int jj = 0; jj < 4; ++jj)
        aoc[rowb + jj * 16 + lr] = f2bf(o[jj][r] * ir[r]);
    }
  }
}

// ---------- bias broadcast fill (covers masked rows exactly) ----------
__global__ __launch_bounds__(256) void k_biasfill(
    const float* __restrict__ bias, float* __restrict__ out) {
  int idx = blockIdx.x * 256 + threadIdx.x;   // 1M threads x float4
  int row = idx >> 8, c4 = idx & 255;
  ((float4*)out)[(size_t)row * 256 + c4] = ((const float4*)bias)[c4];
}

// ---------- GEMM2 on compacted rows: out[perm[slot]] = aoc @ w_out + b_out ----------
// 1D grid 512; XCD-affine: xcd owns col-tile xcd; BK=64.
__global__ __launch_bounds__(256) void k_gemm_out(
    const unsigned short* __restrict__ A, const unsigned short* __restrict__ Bt,
    const unsigned short* __restrict__ perm, const int* __restrict__ nvb,
    const float* __restrict__ bias, float* __restrict__ C) {
  __shared__ unsigned short SH[12288];        // 24 KB: As[64][64] | Bs[128][64]
  unsigned short* As = SH;
  unsigned short* Bs = SH + 4096;
  const int lid = blockIdx.x;
  const int col = lid & 7;
  const int rt = lid >> 3;                    // 0..63
  const int b = rt >> 4, mt = rt & 15;
  const int nv = nvb[b];
  if (mt * 64 >= nv) return;
  const int bm0 = mt * 64;
  const int bn0 = col * 128;
  const size_t abase = ((size_t)(b * 1024 + bm0)) * 1024;
  const int t = threadIdx.x;
  const int lane = t & 63, wave = t >> 6;
  const int wm = (wave >> 1) * 32, wn = (wave & 1) * 64;
  const int lr = lane & 15, quad = lane >> 4;
  const int sw = lr & 7;
  f32x4 acc[2][4] = {};
  for (int k0 = 0; k0 < 1024; k0 += 64) {
    __syncthreads();
#pragma unroll
    for (int j = 0; j < 2; ++j) {
      int idx = t + j * 256;                  // 0..511 (A: 64 rows x 8 chunks)
      int row = idx >> 3;
      int g = (idx ^ row) & 7;
      ASYNC16(&A[abase + (size_t)row * 1024 + k0 + g * 8], &As[idx * 8]);
    }
#pragma unroll
    for (int j = 0; j < 4; ++j) {
      int idx = t + j * 256;                  // 0..1023 (B: 128 rows x 8 chunks)
      int row = idx >> 3;
      int g = (idx ^ row) & 7;
      ASYNC16(&Bt[((size_t)(bn0 + row)) * 1024 + k0 + g * 8], &Bs[idx * 8]);
    }
    __syncthreads();
#pragma unroll
    for (int ks = 0; ks < 2; ++ks) {
      bf16x8 af[2], bfr[4];
#pragma unroll
      for (int i = 0; i < 2; ++i)
        af[i] = *(const bf16x8*)(&As[(wm + i * 16 + lr) * 64 + (((ks * 4 + quad) ^ sw)) * 8]);
#pragma unroll
      for (int j = 0; j < 4; ++j)
        bfr[j] = *(const bf16x8*)(&Bs[(wn + j * 16 + lr) * 64 + (((ks * 4 + quad) ^ sw)) * 8]);
#pragma unroll
      for (int i = 0; i < 2; ++i)
#pragma unroll
        for (int j = 0; j < 4; ++j)
          acc[i][j] = MFMA16(af[i], bfr[j], acc[i][j]);
    }
  }
#pragma unroll
  for (int i = 0; i < 2; ++i)
#pragma unroll
    for (int r = 0; r < 4; ++r) {
      int slot = bm0 + wm + i * 16 + quad * 4 + r;
      if (slot < nv) {
        int tok = perm[b * 1024 + slot];
        size_t rowb = ((size_t)(b * 1024 + tok)) * 1024;
#pragma unroll
        for (int j = 0; j < 4; ++j) {
          int c = bn0 + wn + j * 16 + lr;
          C[rowb + c] = acc[i][j][r] + bias[c];
        }
      }
    }
}

extern "C" void kernel_launch(void* const* d_in, const int* in_sizes, int n_in,
                              void* d_out, int out_size, void* d_ws, size_t ws_size,
                              hipStream_t stream) {
  const float* x    = (const float*)d_in[0];
  const float* mask = (const float*)d_in[1];
  const float* wqkv = (const float*)d_in[2];
  const float* wout = (const float*)d_in[3];
  const float* bout = (const float*)d_in[4];
  float* out = (float*)d_out;
  char* ws = (char*)d_ws;
  // layout (40 MB + small, with aliasing):
  unsigned short* xc    = (unsigned short*)(ws);                      // [0,8)   compacted x bf16 (dead after gemm1)
  unsigned short* vtc   = (unsigned short*)(ws);                      //         alias: V^T compacted (vtrans->attn)
  unsigned short* wqkvt = (unsigned short*)(ws + (size_t)( 8 << 20)); // [8,14)
  unsigned short* woutt = (unsigned short*)(ws + (size_t)(14 << 20)); // [14,16)
  unsigned short* qcmp  = (unsigned short*)(ws + (size_t)(16 << 20)); // [16,24)
  unsigned short* kcmp  = (unsigned short*)(ws + (size_t)(24 << 20)); // [24,32)
  unsigned short* vcmp  = (unsigned short*)(ws + (size_t)(32 << 20)); // [32,40)  (dead after vtrans)
  unsigned short* aoc   = (unsigned short*)(ws + (size_t)(32 << 20)); //          alias: attn out compact (attn->gemm2)
  unsigned short* perm  = (unsigned short*)(ws + (size_t)(40 << 20));            // 8 KB
  int*            nvb   = (int*)           (ws + (size_t)(40 << 20) + 8192);    // 16 B

  k_scan<<<4, 1024, 0, stream>>>(mask, perm, nvb);
  k_cvtg<<<4096, 256, 0, stream>>>(x, perm, nvb, xc);
  k_transpose_cvt<<<dim3(96, 32), 256, 0, stream>>>(wqkv, wqkvt, 1024, 3072);
  k_transpose_cvt<<<dim3(32, 32), 256, 0, stream>>>(wout, woutt, 1024, 1024);
  k_gemm_qkv<<<768, 256, 0, stream>>>(xc, wqkvt, nvb, qcmp, kcmp, vcmp);
  k_vtrans<<<dim3(2, 32, 64), 256, 0, stream>>>(vcmp, vtc, nvb);
  k_padzero<<<4, 256, 0, stream>>>(aoc, nvb);
  k_attn<<<1024, 256, 0, stream>>>(qcmp, kcmp, vtc, nvb, aoc);
  k_biasfill<<<4096, 256, 0, stream>>>(bout, out);
  k_gemm_out<<<512, 256, 0, stream>>>(aoc, woutt, perm, nvb, bout, out);
}

// Round 6
// 149.140 us; speedup vs baseline: 2.3844x; 1.1061x over previous
//
#include <hip/hip_runtime.h>

#define INF __builtin_inff()

typedef __attribute__((ext_vector_type(8))) short bf16x8;
typedef __attribute__((ext_vector_type(4))) short s16x4;
typedef __attribute__((ext_vector_type(4))) float f32x4;
typedef __attribute__((ext_vector_type(8))) unsigned short u16x8;
typedef __attribute__((ext_vector_type(4))) unsigned short u16x4;

#define MFMA16(a, b, c) __builtin_amdgcn_mfma_f32_16x16x32_bf16(a, b, c, 0, 0, 0)

// async global->LDS, 16B per lane; LDS dest = wave-uniform base + lane*16
#define ASYNC16(g, l) __builtin_amdgcn_global_load_lds( \
    (const __attribute__((address_space(1))) unsigned int*)(const void*)(g), \
    (__attribute__((address_space(3))) unsigned int*)(void*)(l), 16, 0, 0)

__device__ __forceinline__ unsigned short f2bf(float f) {
  union { float f; unsigned u; } v; v.f = f;
  unsigned r = v.u + 0x7fffu + ((v.u >> 16) & 1u);   // RNE
  return (unsigned short)(r >> 16);
}

// ---------- mask scan: perm[b][0..nv)=valid tokens, perm[b][nv..1024)=masked tokens ----------
__global__ __launch_bounds__(1024) void k_scan(
    const float* __restrict__ mask, unsigned short* __restrict__ perm, int* __restrict__ nv) {
  __shared__ int wsum[16];
  __shared__ int woff[16];
  const int b = blockIdx.x, t = threadIdx.x;
  const int wid = t >> 6, lane = t & 63;
  const bool valid = (mask[b * 1024 + t] != 0.f);
  unsigned long long bal = __ballot(valid);
  int pre = __popcll(bal & ((1ull << lane) - 1ull));
  if (lane == 0) wsum[wid] = __popcll(bal);
  __syncthreads();
  if (t < 16) { int s = 0; for (int i = 0; i < t; ++i) s += wsum[i]; woff[t] = s; }
  __syncthreads();
  const int nvt = woff[15] + wsum[15];
  const int p = woff[wid] + pre;               // # valid before t
  perm[b * 1024 + (valid ? p : nvt + (t - p))] = (unsigned short)t;
  if (t == 0) nv[b] = nvt;
}

// ---------- gather-convert x rows into compacted xc (zero-pad to ceil128) ----------
__global__ __launch_bounds__(256) void k_cvtg(
    const float* __restrict__ x, const unsigned short* __restrict__ perm,
    const int* __restrict__ nvb, unsigned short* __restrict__ xc) {
  const int id = blockIdx.x;
  const int b = id >> 10, slot = id & 1023;
  const int nv = nvb[b];
  if (slot >= ((nv + 127) & ~127)) return;
  const int t = threadIdx.x;
  u16x4 o;
  if (slot < nv) {
    int tok = perm[b * 1024 + slot];
    float4 f = ((const float4*)(x + ((size_t)(b * 1024 + tok)) * 1024))[t];
    o[0] = f2bf(f.x); o[1] = f2bf(f.y); o[2] = f2bf(f.z); o[3] = f2bf(f.w);
  } else {
    o[0] = o[1] = o[2] = o[3] = 0;
  }
  ((u16x4*)(xc + ((size_t)(b * 1024 + slot)) * 1024))[t] = o;
}

// ---------- both weight transposes (fp32 [R][C] -> bf16 [C][R]) in one launch ----------
__global__ __launch_bounds__(256) void k_wtrans(
    const float* __restrict__ wqkv, const float* __restrict__ wout,
    unsigned short* __restrict__ wqkvt, unsigned short* __restrict__ woutt) {
  __shared__ float tile[32][33];
  int id = blockIdx.x;
  const float* src; unsigned short* dst; int C, bc, br;
  if (id < 3072) { src = wqkv;  dst = wqkvt; C = 3072; bc = (id % 96) * 32; br = (id / 96) * 32; }
  else { id -= 3072; src = wout; dst = woutt; C = 1024; bc = (id & 31) * 32; br = (id >> 5) * 32; }
  const int R = 1024;
  const int tx = threadIdx.x & 31, ty = threadIdx.x >> 5;
#pragma unroll
  for (int i = 0; i < 32; i += 8)
    tile[ty + i][tx] = src[(size_t)(br + ty + i) * C + bc + tx];
  __syncthreads();
#pragma unroll
  for (int i = 0; i < 32; i += 8)
    dst[(size_t)(bc + ty + i) * R + br + tx] = f2bf(tile[tx][ty + i]);
}

// ---------- GEMM1 (double-buffered): qkv = xc @ w_qkv -> qcmp/kcmp + V^T fused ----------
// grid 768; XCD-affine: xcd owns cols [3*xcd, 3*xcd+3); BK=64; 2x32KB LDS buffers.
__global__ __launch_bounds__(256) void k_gemm_qkv(
    const unsigned short* __restrict__ A, const unsigned short* __restrict__ Bt,
    const int* __restrict__ nvb,
    unsigned short* __restrict__ qcmp, unsigned short* __restrict__ kcmp,
    unsigned short* __restrict__ vt) {
  __shared__ unsigned short SH[32768];        // 64 KB: 2 x (As[128][64] | Bs[128][64])
  const int lid = blockIdx.x;
  const int xcd = lid & 7, i6 = lid >> 3;
  const int colt = xcd * 3 + (i6 % 3);        // 0..23
  const int rowt = i6 / 3;                    // 0..31
  const int b = rowt >> 3, mt = rowt & 7;
  const int nv = nvb[b];
  if (mt * 128 >= nv) return;
  const int bm0 = mt * 128;
  const int bn0 = colt * 128;
  const size_t abase = ((size_t)(b * 1024 + bm0)) * 1024;
  const int t = threadIdx.x;
  const int lane = t & 63, wave = t >> 6;
  const int wm = (wave >> 1) * 64, wn = (wave & 1) * 64;
  const int lr = lane & 15, quad = lane >> 4;
  const int sw = lr & 7;
  f32x4 acc[4][4] = {};
  auto stage = [&](int pp, int k0) {
    unsigned short* As = SH + pp * 16384;
    unsigned short* Bs = As + 8192;
#pragma unroll
    for (int j = 0; j < 4; ++j) {
      int idx = t + j * 256;
      int row = idx >> 3;
      int g = (idx ^ row) & 7;                // chunk XOR swizzle
      ASYNC16(&A[abase + (size_t)row * 1024 + k0 + g * 8], &As[idx * 8]);
      ASYNC16(&Bt[((size_t)(bn0 + row)) * 1024 + k0 + g * 8], &Bs[idx * 8]);
    }
  };
  stage(0, 0);
  for (int it = 0; it < 16; ++it) {
    const int pp = it & 1;
    __syncthreads();                          // drains DMA for buf pp (in flight during prev compute)
    if (it + 1 < 16) stage(1 - pp, (it + 1) * 64);
    const unsigned short* As = SH + pp * 16384;
    const unsigned short* Bs = As + 8192;
#pragma unroll
    for (int ks = 0; ks < 2; ++ks) {
      bf16x8 af[4], bfr[4];
#pragma unroll
      for (int i = 0; i < 4; ++i)
        af[i] = *(const bf16x8*)(&As[(wm + i * 16 + lr) * 64 + (((ks * 4 + quad) ^ sw)) * 8]);
#pragma unroll
      for (int j = 0; j < 4; ++j)
        bfr[j] = *(const bf16x8*)(&Bs[(wn + j * 16 + lr) * 64 + (((ks * 4 + quad) ^ sw)) * 8]);
#pragma unroll
      for (int i = 0; i < 4; ++i)
#pragma unroll
        for (int j = 0; j < 4; ++j)
          acc[i][j] = MFMA16(af[i], bfr[j], acc[i][j]);
    }
  }
  // epilogue: repack 64-row halves into SH[64][136]; Q/K row stores, V transposed stores
  const int sec = bn0 >> 10;                  // 0=Q 1=K 2=V (uniform)
  const int js0 = bn0 & 1023;
#pragma unroll
  for (int hh = 0; hh < 2; ++hh) {
    __syncthreads();
    if ((wave >> 1) == hh) {
#pragma unroll
      for (int i = 0; i < 4; ++i)
#pragma unroll
        for (int j = 0; j < 4; ++j)
#pragma unroll
          for (int r = 0; r < 4; ++r)
            SH[(i * 16 + quad * 4 + r) * 136 + wn + j * 16 + lr] = f2bf(acc[i][j][r]);
    }
    __syncthreads();
    if (sec < 2) {
      unsigned short* dstT = sec ? kcmp : qcmp;
#pragma unroll
      for (int rr = 0; rr < 4; ++rr) {
        int lrow = (t >> 4) + rr * 16;        // 0..63
        int ck = t & 15;
        int slot = bm0 + hh * 64 + lrow;
        int js = js0 + ck * 8;
        int h = js >> 6, d = js & 63;
        u16x8 v = *(u16x8*)(&SH[lrow * 136 + ck * 8]);
        *(u16x8*)(&dstT[(((size_t)(b * 16 + h)) * 1024 + slot) * 64 + d]) = v;
      }
    } else {
      // V: write transposed [bh][d][slot] directly from LDS columns
      const int c = t & 127, seg = t >> 7;    // 2 threads/col, 32 slots each
      const int js = js0 + c, h = js >> 6, d = js & 63;
      unsigned short* vrow =
          &vt[(((size_t)(b * 16 + h)) * 64 + d) * 1024 + bm0 + hh * 64 + seg * 32];
#pragma unroll
      for (int s4 = 0; s4 < 4; ++s4) {
        u16x8 v;
#pragma unroll
        for (int s = 0; s < 8; ++s) v[s] = SH[(seg * 32 + s4 * 8 + s) * 136 + c];
        *(u16x8*)(vrow + s4 * 8) = v;
      }
    }
  }
}

// ---------- Flash attention (double-buffered K/V staging) over compacted tokens ----------
__global__ __launch_bounds__(256, 3) void k_attn(
    const unsigned short* __restrict__ qcmp, const unsigned short* __restrict__ kcmp,
    const unsigned short* __restrict__ vtc, const int* __restrict__ nvb,
    unsigned short* __restrict__ aoc) {
  __shared__ unsigned short Ks[2][4096];
  __shared__ unsigned short Vs[2][4096];
  __shared__ unsigned short P[4][16 * 72];
  const int bx = blockIdx.x;
  const int bh = (bx & 7) + 8 * (bx >> 7);   // XCD-local bh grouping
  const int qcb = (bx >> 3) & 15;
  const int b = bh >> 4;
  const int nv = nvb[b];
  if (qcb * 64 >= nv) return;
  const int t = threadIdx.x;
  const int wave = t >> 6, lane = t & 63;
  const int lr = lane & 15, quad = lane >> 4;
  const int q0 = qcb * 64 + wave * 16;
  const unsigned short* qp = qcmp + ((size_t)bh << 16);
  const unsigned short* kp = kcmp + ((size_t)bh << 16);
  const unsigned short* vp = vtc + ((size_t)bh << 16);
  unsigned short* Pw = P[wave];
  bf16x8 qv0 = *(const bf16x8*)(qp + (q0 + lr) * 64 + quad * 8);
  bf16x8 qv1 = *(const bf16x8*)(qp + (q0 + lr) * 64 + 32 + quad * 8);
  float m = -INF, l = 0.f;
  f32x4 o[4] = {};
  const int sw = lr & 7;
  const int nk = (nv + 63) >> 6;
  auto stage = [&](int pp, int kc0) {
#pragma unroll
    for (int ld = 0; ld < 2; ++ld) {
      int idx = t + ld * 256;
      int row = idx >> 3;
      int g = (idx ^ row) & 7;
      ASYNC16(kp + (kc0 + row) * 64 + g * 8, &Ks[pp][idx * 8]);
      ASYNC16(vp + (size_t)row * 1024 + kc0 + g * 8, &Vs[pp][idx * 8]);
    }
  };
  stage(0, 0);
  for (int it = 0; it < nk; ++it) {
    const int pp = it & 1;
    const int kc0 = it * 64;
    __syncthreads();
    if (it + 1 < nk) stage(1 - pp, kc0 + 64);
    f32x4 st[4];
#pragma unroll
    for (int tt = 0; tt < 4; ++tt) {
      int krow = tt * 16 + lr;
      bf16x8 k0 = *(const bf16x8*)(&Ks[pp][krow * 64 + ((quad ^ sw)) * 8]);
      bf16x8 k1 = *(const bf16x8*)(&Ks[pp][krow * 64 + (((4 + quad) ^ sw)) * 8]);
      f32x4 c = {};
      c = MFMA16(k0, qv0, c);
      c = MFMA16(k1, qv1, c);
      st[tt] = c;
    }
    float tm = -INF;
#pragma unroll
    for (int tt = 0; tt < 4; ++tt) {
#pragma unroll
      for (int r = 0; r < 4; ++r) {
        int slot = kc0 + tt * 16 + quad * 4 + r;
        float v = (slot < nv) ? st[tt][r] * 0.125f : -INF;
        st[tt][r] = v;
        tm = fmaxf(tm, v);
      }
    }
    tm = fmaxf(tm, __shfl_xor(tm, 16));
    tm = fmaxf(tm, __shfl_xor(tm, 32));
    float mn = fmaxf(m, tm);
    float alpha = __expf(m - mn);
    if (m == -INF) alpha = 1.f;
    float ps = 0.f;
#pragma unroll
    for (int tt = 0; tt < 4; ++tt) {
      s16x4 pv;
#pragma unroll
      for (int r = 0; r < 4; ++r) {
        float pe = __expf(st[tt][r] - mn);
        ps += pe;
        pv[r] = (short)f2bf(pe);
      }
      *(s16x4*)(&Pw[lr * 72 + tt * 16 + quad * 4]) = pv;
    }
    ps += __shfl_xor(ps, 16);
    ps += __shfl_xor(ps, 32);
    l = l * alpha + ps;
    m = mn;
    float ar[4];
#pragma unroll
    for (int r = 0; r < 4; ++r) ar[r] = __shfl(alpha, quad * 4 + r);
#pragma unroll
    for (int jj = 0; jj < 4; ++jj)
#pragma unroll
      for (int r = 0; r < 4; ++r) o[jj][r] *= ar[r];
#pragma unroll
    for (int sh = 0; sh < 2; ++sh) {
      bf16x8 pa = *(const bf16x8*)(&Pw[lr * 72 + sh * 32 + quad * 8]);
#pragma unroll
      for (int jj = 0; jj < 4; ++jj) {
        bf16x8 vbf = *(const bf16x8*)(&Vs[pp][(jj * 16 + lr) * 64 + (((sh * 4 + quad) ^ sw)) * 8]);
        o[jj] = MFMA16(pa, vbf, o[jj]);
      }
    }
  }
  float inv = 1.f / l;
  float ir[4];
#pragma unroll
  for (int r = 0; r < 4; ++r) ir[r] = __shfl(inv, quad * 4 + r);
  const int h = bh & 15;
#pragma unroll
  for (int r = 0; r < 4; ++r) {
    int slot = q0 + quad * 4 + r;
    if (slot < nv) {
      size_t rowb = ((size_t)(b * 1024 + slot)) * 1024 + h * 64;
#pragma unroll
      for (int jj = 0; jj < 4; ++jj)
        aoc[rowb + jj * 16 + lr] = f2bf(o[jj][r] * ir[r]);
    }
  }
}

// ---------- bias fill for masked rows only (perm[b][nv..1024) = masked tokens) ----------
__global__ __launch_bounds__(256) void k_biasfill(
    const float* __restrict__ bias, const unsigned short* __restrict__ perm,
    const int* __restrict__ nvb, float* __restrict__ out) {
  const int b = blockIdx.x >> 10, slot = blockIdx.x & 1023;
  if (slot < nvb[b]) return;
  const int tok = perm[b * 1024 + slot];
  ((float4*)(out + ((size_t)(b * 1024 + tok)) * 1024))[threadIdx.x] =
      ((const float4*)bias)[threadIdx.x];
}

// ---------- GEMM2 (double-buffered): out[perm[slot]] = aoc @ w_out + b_out ----------
__global__ __launch_bounds__(256) void k_gemm_out(
    const unsigned short* __restrict__ A, const unsigned short* __restrict__ Bt,
    const unsigned short* __restrict__ perm, const int* __restrict__ nvb,
    const float* __restrict__ bias, float* __restrict__ C) {
  __shared__ unsigned short SH[24576];        // 48 KB: 2 x (As[64][64] | Bs[128][64])
  const int lid = blockIdx.x;
  const int col = lid & 7;                    // XCD-affine col tile
  const int rt = lid >> 3;
  const int b = rt >> 4, mt = rt & 15;
  const int nv = nvb[b];
  if (mt * 64 >= nv) return;
  const int bm0 = mt * 64;
  const int bn0 = col * 128;
  const size_t abase = ((size_t)(b * 1024 + bm0)) * 1024;
  const int t = threadIdx.x;
  const int lane = t & 63, wave = t >> 6;
  const int wm = (wave >> 1) * 32, wn = (wave & 1) * 64;
  const int lr = lane & 15, quad = lane >> 4;
  const int sw = lr & 7;
  f32x4 acc[2][4] = {};
  auto stage = [&](int pp, int k0) {
    unsigned short* As = SH + pp * 12288;
    unsigned short* Bs = As + 4096;
#pragma unroll
    for (int j = 0; j < 2; ++j) {
      int idx = t + j * 256;                  // A: 64 rows x 8 chunks
      int row = idx >> 3;
      int g = (idx ^ row) & 7;
      ASYNC16(&A[abase + (size_t)row * 1024 + k0 + g * 8], &As[idx * 8]);
    }
#pragma unroll
    for (int j = 0; j < 4; ++j) {
      int idx = t + j * 256;                  // B: 128 rows x 8 chunks
      int row = idx >> 3;
      int g = (idx ^ row) & 7;
      ASYNC16(&Bt[((size_t)(bn0 + row)) * 1024 + k0 + g * 8], &Bs[idx * 8]);
    }
  };
  stage(0, 0);
  for (int it = 0; it < 16; ++it) {
    const int pp = it & 1;
    __syncthreads();
    if (it + 1 < 16) stage(1 - pp, (it + 1) * 64);
    const unsigned short* As = SH + pp * 12288;
    const unsigned short* Bs = As + 4096;
#pragma unroll
    for (int ks = 0; ks < 2; ++ks) {
      bf16x8 af[2], bfr[4];
#pragma unroll
      for (int i = 0; i < 2; ++i)
        af[i] = *(const bf16x8*)(&As[(wm + i * 16 + lr) * 64 + (((ks * 4 + quad) ^ sw)) * 8]);
#pragma unroll
      for (int j = 0; j < 4; ++j)
        bfr[j] = *(const bf16x8*)(&Bs[(wn + j * 16 + lr) * 64 + (((ks * 4 + quad) ^ sw)) * 8]);
#pragma unroll
      for (int i = 0; i < 2; ++i)
#pragma unroll
        for (int j = 0; j < 4; ++j)
          acc[i][j] = MFMA16(af[i], bfr[j], acc[i][j]);
    }
  }
#pragma unroll
  for (int i = 0; i < 2; ++i)
#pragma unroll
    for (int r = 0; r < 4; ++r) {
      int slot = bm0 + wm + i * 16 + quad * 4 + r;
      if (slot < nv) {
        int tok = perm[b * 1024 + slot];
        size_t rowb = ((size_t)(b * 1024 + tok)) * 1024;
#pragma unroll
        for (int j = 0; j < 4; ++j) {
          int c = bn0 + wn + j * 16 + lr;
          C[rowb + c] = acc[i][j][r] + bias[c];
        }
      }
    }
}

extern "C" void kernel_launch(void* const* d_in, const int* in_sizes, int n_in,
                              void* d_out, int out_size, void* d_ws, size_t ws_size,
                              hipStream_t stream) {
  const float* x    = (const float*)d_in[0];
  const float* mask = (const float*)d_in[1];
  const float* wqkv = (const float*)d_in[2];
  const float* wout = (const float*)d_in[3];
  const float* bout = (const float*)d_in[4];
  float* out = (float*)d_out;
  char* ws = (char*)d_ws;
  // layout (40 MB + 8.2 KB):
  unsigned short* xc    = (unsigned short*)(ws);                      // [0,8)  compacted x (dead after gemm1)
  unsigned short* aoc   = (unsigned short*)(ws);                      //        alias: attn out compact
  unsigned short* wqkvt = (unsigned short*)(ws + (size_t)( 8 << 20)); // [8,14)
  unsigned short* woutt = (unsigned short*)(ws + (size_t)(14 << 20)); // [14,16)
  unsigned short* qcmp  = (unsigned short*)(ws + (size_t)(16 << 20)); // [16,24)
  unsigned short* kcmp  = (unsigned short*)(ws + (size_t)(24 << 20)); // [24,32)
  unsigned short* vt    = (unsigned short*)(ws + (size_t)(32 << 20)); // [32,40) V^T compact [bh][d][slot]
  unsigned short* perm  = (unsigned short*)(ws + (size_t)(40 << 20));           // 8 KB
  int*            nvb   = (int*)           (ws + (size_t)(40 << 20) + 8192);    // 16 B

  k_scan<<<4, 1024, 0, stream>>>(mask, perm, nvb);
  k_cvtg<<<4096, 256, 0, stream>>>(x, perm, nvb, xc);
  k_wtrans<<<4096, 256, 0, stream>>>(wqkv, wout, wqkvt, woutt);
  k_gemm_qkv<<<768, 256, 0, stream>>>(xc, wqkvt, nvb, qcmp, kcmp, vt);
  k_attn<<<1024, 256, 0, stream>>>(qcmp, kcmp, vt, nvb, aoc);
  k_biasfill<<<4096, 256, 0, stream>>>(bout, perm, nvb, out);
  k_gemm_out<<<512, 256, 0, stream>>>(aoc, woutt, perm, nvb, bout, out);
}

// Round 7
// 145.607 us; speedup vs baseline: 2.4423x; 1.0243x over previous
//
#include <hip/hip_runtime.h>

#define INF __builtin_inff()

typedef __attribute__((ext_vector_type(8))) short bf16x8;
typedef __attribute__((ext_vector_type(4))) short s16x4;
typedef __attribute__((ext_vector_type(4))) float f32x4;
typedef __attribute__((ext_vector_type(8))) unsigned short u16x8;
typedef __attribute__((ext_vector_type(4))) unsigned short u16x4;

#define MFMA16(a, b, c) __builtin_amdgcn_mfma_f32_16x16x32_bf16(a, b, c, 0, 0, 0)

// async global->LDS, 16B per lane; LDS dest = wave-uniform base + lane*16
#define ASYNC16(g, l) __builtin_amdgcn_global_load_lds( \
    (const __attribute__((address_space(1))) unsigned int*)(const void*)(g), \
    (__attribute__((address_space(3))) unsigned int*)(void*)(l), 16, 0, 0)

__device__ __forceinline__ unsigned short f2bf(float f) {
  union { float f; unsigned u; } v; v.f = f;
  unsigned r = v.u + 0x7fffu + ((v.u >> 16) & 1u);   // RNE
  return (unsigned short)(r >> 16);
}

// ================= PREP: scan (4) | weight transposes (4096) | x gather-cvt (1024) ===========
__global__ __launch_bounds__(256) void k_prep(
    const float* __restrict__ x, const float* __restrict__ mask,
    const float* __restrict__ wqkv, const float* __restrict__ wout,
    unsigned short* __restrict__ xc, unsigned short* __restrict__ wqkvt,
    unsigned short* __restrict__ woutt, unsigned short* __restrict__ perm,
    int* __restrict__ nvb) {
  __shared__ union {
    float tile[32][33];
    struct { unsigned short lperm[1024]; int wtot[4]; } sc;
  } sh;
  const int lid = blockIdx.x;
  const int t = threadIdx.x, lane = t & 63, wid = t >> 6;

  if (lid >= 4 && lid < 4100) {
    // ---- weight transpose fp32 [R][C] -> bf16 [C][R]
    int id = lid - 4;
    const float* src; unsigned short* dst; int C, bc, br;
    if (id < 3072) { src = wqkv; dst = wqkvt; C = 3072; bc = (id % 96) * 32; br = (id / 96) * 32; }
    else { id -= 3072; src = wout; dst = woutt; C = 1024; bc = (id & 31) * 32; br = (id >> 5) * 32; }
    const int tx = t & 31, ty = t >> 5;
#pragma unroll
    for (int i = 0; i < 32; i += 8)
      sh.tile[ty + i][tx] = src[(size_t)(br + ty + i) * C + bc + tx];
    __syncthreads();
#pragma unroll
    for (int i = 0; i < 32; i += 8)
      dst[(size_t)(bc + ty + i) * 1024 + br + tx] = f2bf(sh.tile[tx][ty + i]);
    return;
  }

  // ---- per-batch mask scan (both remaining roles need it)
  const int b = (lid < 4) ? lid : ((lid - 4100) >> 8);
  float4 mv = ((const float4*)(mask + b * 1024))[t];
  int v0 = mv.x != 0.f, v1 = mv.y != 0.f, v2 = mv.z != 0.f, v3 = mv.w != 0.f;
  int cnt = v0 + v1 + v2 + v3;
  int pre = cnt;
#pragma unroll
  for (int d = 1; d < 64; d <<= 1) { int n = __shfl_up(pre, d); if (lane >= d) pre += n; }
  if (lane == 63) sh.sc.wtot[wid] = pre;
  __syncthreads();
  int base = 0;
#pragma unroll
  for (int i = 0; i < 4; ++i) if (i < wid) base += sh.sc.wtot[i];
  const int nvt = sh.sc.wtot[0] + sh.sc.wtot[1] + sh.sc.wtot[2] + sh.sc.wtot[3];
  int ex = base + pre - cnt;                      // # valid before token 4t
  int vv[4] = { v0, v1, v2, v3 };

  if (lid < 4) {
    // ---- scan writeback: perm[0..nv)=valid, [nv..1024)=masked
#pragma unroll
    for (int j = 0; j < 4; ++j) {
      int tok = t * 4 + j;
      if (vv[j]) { perm[b * 1024 + ex] = (unsigned short)tok; ++ex; }
      else         perm[b * 1024 + nvt + (tok - ex)] = (unsigned short)tok;
    }
    if (t == 0) nvb[b] = nvt;
    return;
  }

  // ---- gather-convert 4 x-rows into compacted xc (zero-pad to ceil128)
#pragma unroll
  for (int j = 0; j < 4; ++j) {
    int tok = t * 4 + j;
    if (vv[j]) { sh.sc.lperm[ex] = (unsigned short)tok; ++ex; }
  }
  __syncthreads();
  const int s0 = ((lid - 4100) & 255) * 4;
  const int ce = (nvt + 127) & ~127;
#pragma unroll
  for (int j = 0; j < 4; ++j) {
    int slot = s0 + j;
    if (slot >= ce) continue;
    u16x4 o;
    if (slot < nvt) {
      int tok = sh.sc.lperm[slot];
      float4 f = ((const float4*)(x + ((size_t)(b * 1024 + tok)) * 1024))[t];
      o[0] = f2bf(f.x); o[1] = f2bf(f.y); o[2] = f2bf(f.z); o[3] = f2bf(f.w);
    } else {
      o[0] = o[1] = o[2] = o[3] = 0;
    }
    ((u16x4*)(xc + ((size_t)(b * 1024 + slot)) * 1024))[t] = o;
  }
}

// ---------- GEMM1 (double-buffered): qkv = xc @ w_qkv -> qcmp/kcmp + V^T fused ----------
__global__ __launch_bounds__(256) void k_gemm_qkv(
    const unsigned short* __restrict__ A, const unsigned short* __restrict__ Bt,
    const int* __restrict__ nvb,
    unsigned short* __restrict__ qcmp, unsigned short* __restrict__ kcmp,
    unsigned short* __restrict__ vt) {
  __shared__ unsigned short SH[32768];        // 64 KB: 2 x (As[128][64] | Bs[128][64])
  const int lid = blockIdx.x;
  const int xcd = lid & 7, i6 = lid >> 3;
  const int colt = xcd * 3 + (i6 % 3);
  const int rowt = i6 / 3;
  const int b = rowt >> 3, mt = rowt & 7;
  const int nv = nvb[b];
  if (mt * 128 >= nv) return;
  const int bm0 = mt * 128;
  const int bn0 = colt * 128;
  const size_t abase = ((size_t)(b * 1024 + bm0)) * 1024;
  const int t = threadIdx.x;
  const int lane = t & 63, wave = t >> 6;
  const int wm = (wave >> 1) * 64, wn = (wave & 1) * 64;
  const int lr = lane & 15, quad = lane >> 4;
  const int sw = lr & 7;
  f32x4 acc[4][4] = {};
  auto stage = [&](int pp, int k0) {
    unsigned short* As = SH + pp * 16384;
    unsigned short* Bs = As + 8192;
#pragma unroll
    for (int j = 0; j < 4; ++j) {
      int idx = t + j * 256;
      int row = idx >> 3;
      int g = (idx ^ row) & 7;                // chunk XOR swizzle
      ASYNC16(&A[abase + (size_t)row * 1024 + k0 + g * 8], &As[idx * 8]);
      ASYNC16(&Bt[((size_t)(bn0 + row)) * 1024 + k0 + g * 8], &Bs[idx * 8]);
    }
  };
  stage(0, 0);
  for (int it = 0; it < 16; ++it) {
    const int pp = it & 1;
    __syncthreads();
    if (it + 1 < 16) stage(1 - pp, (it + 1) * 64);
    const unsigned short* As = SH + pp * 16384;
    const unsigned short* Bs = As + 8192;
#pragma unroll
    for (int ks = 0; ks < 2; ++ks) {
      bf16x8 af[4], bfr[4];
#pragma unroll
      for (int i = 0; i < 4; ++i)
        af[i] = *(const bf16x8*)(&As[(wm + i * 16 + lr) * 64 + (((ks * 4 + quad) ^ sw)) * 8]);
#pragma unroll
      for (int j = 0; j < 4; ++j)
        bfr[j] = *(const bf16x8*)(&Bs[(wn + j * 16 + lr) * 64 + (((ks * 4 + quad) ^ sw)) * 8]);
#pragma unroll
      for (int i = 0; i < 4; ++i)
#pragma unroll
        for (int j = 0; j < 4; ++j)
          acc[i][j] = MFMA16(af[i], bfr[j], acc[i][j]);
    }
  }
  // epilogue: repack 64-row halves into SH[64][136]; Q/K row stores, V transposed stores
  const int sec = bn0 >> 10;
  const int js0 = bn0 & 1023;
#pragma unroll
  for (int hh = 0; hh < 2; ++hh) {
    __syncthreads();
    if ((wave >> 1) == hh) {
#pragma unroll
      for (int i = 0; i < 4; ++i)
#pragma unroll
        for (int j = 0; j < 4; ++j)
#pragma unroll
          for (int r = 0; r < 4; ++r)
            SH[(i * 16 + quad * 4 + r) * 136 + wn + j * 16 + lr] = f2bf(acc[i][j][r]);
    }
    __syncthreads();
    if (sec < 2) {
      unsigned short* dstT = sec ? kcmp : qcmp;
#pragma unroll
      for (int rr = 0; rr < 4; ++rr) {
        int lrow = (t >> 4) + rr * 16;
        int ck = t & 15;
        int slot = bm0 + hh * 64 + lrow;
        int js = js0 + ck * 8;
        int h = js >> 6, d = js & 63;
        u16x8 v = *(u16x8*)(&SH[lrow * 136 + ck * 8]);
        *(u16x8*)(&dstT[(((size_t)(b * 16 + h)) * 1024 + slot) * 64 + d]) = v;
      }
    } else {
      const int c = t & 127, seg = t >> 7;
      const int js = js0 + c, h = js >> 6, d = js & 63;
      unsigned short* vrow =
          &vt[(((size_t)(b * 16 + h)) * 64 + d) * 1024 + bm0 + hh * 64 + seg * 32];
#pragma unroll
      for (int s4 = 0; s4 < 4; ++s4) {
        u16x8 v;
#pragma unroll
        for (int s = 0; s < 8; ++s) v[s] = SH[(seg * 32 + s4 * 8 + s) * 136 + c];
        *(u16x8*)(vrow + s4 * 8) = v;
      }
    }
  }
}

// ---------- Flash attention (double-buffered K/V staging) over compacted tokens ----------
__global__ __launch_bounds__(256, 3) void k_attn(
    const unsigned short* __restrict__ qcmp, const unsigned short* __restrict__ kcmp,
    const unsigned short* __restrict__ vtc, const int* __restrict__ nvb,
    unsigned short* __restrict__ aoc) {
  __shared__ unsigned short Ks[2][4096];
  __shared__ unsigned short Vs[2][4096];
  __shared__ unsigned short P[4][16 * 72];
  const int bx = blockIdx.x;
  const int bh = (bx & 7) + 8 * (bx >> 7);   // XCD-local bh grouping
  const int qcb = (bx >> 3) & 15;
  const int b = bh >> 4;
  const int nv = nvb[b];
  if (qcb * 64 >= nv) return;
  const int t = threadIdx.x;
  const int wave = t >> 6, lane = t & 63;
  const int lr = lane & 15, quad = lane >> 4;
  const int q0 = qcb * 64 + wave * 16;
  const unsigned short* qp = qcmp + ((size_t)bh << 16);
  const unsigned short* kp = kcmp + ((size_t)bh << 16);
  const unsigned short* vp = vtc + ((size_t)bh << 16);
  unsigned short* Pw = P[wave];
  bf16x8 qv0 = *(const bf16x8*)(qp + (q0 + lr) * 64 + quad * 8);
  bf16x8 qv1 = *(const bf16x8*)(qp + (q0 + lr) * 64 + 32 + quad * 8);
  float m = -INF, l = 0.f;
  f32x4 o[4] = {};
  const int sw = lr & 7;
  const int nk = (nv + 63) >> 6;
  auto stage = [&](int pp, int kc0) {
#pragma unroll
    for (int ld = 0; ld < 2; ++ld) {
      int idx = t + ld * 256;
      int row = idx >> 3;
      int g = (idx ^ row) & 7;
      ASYNC16(kp + (kc0 + row) * 64 + g * 8, &Ks[pp][idx * 8]);
      ASYNC16(vp + (size_t)row * 1024 + kc0 + g * 8, &Vs[pp][idx * 8]);
    }
  };
  stage(0, 0);
  for (int it = 0; it < nk; ++it) {
    const int pp = it & 1;
    const int kc0 = it * 64;
    __syncthreads();
    if (it + 1 < nk) stage(1 - pp, kc0 + 64);
    f32x4 st[4];
#pragma unroll
    for (int tt = 0; tt < 4; ++tt) {
      int krow = tt * 16 + lr;
      bf16x8 k0 = *(const bf16x8*)(&Ks[pp][krow * 64 + ((quad ^ sw)) * 8]);
      bf16x8 k1 = *(const bf16x8*)(&Ks[pp][krow * 64 + (((4 + quad) ^ sw)) * 8]);
      f32x4 c = {};
      c = MFMA16(k0, qv0, c);
      c = MFMA16(k1, qv1, c);
      st[tt] = c;
    }
    float tm = -INF;
#pragma unroll
    for (int tt = 0; tt < 4; ++tt) {
#pragma unroll
      for (int r = 0; r < 4; ++r) {
        int slot = kc0 + tt * 16 + quad * 4 + r;
        float v = (slot < nv) ? st[tt][r] * 0.125f : -INF;
        st[tt][r] = v;
        tm = fmaxf(tm, v);
      }
    }
    tm = fmaxf(tm, __shfl_xor(tm, 16));
    tm = fmaxf(tm, __shfl_xor(tm, 32));
    float mn = fmaxf(m, tm);
    float alpha = __expf(m - mn);
    if (m == -INF) alpha = 1.f;
    float ps = 0.f;
#pragma unroll
    for (int tt = 0; tt < 4; ++tt) {
      s16x4 pv;
#pragma unroll
      for (int r = 0; r < 4; ++r) {
        float pe = __expf(st[tt][r] - mn);
        ps += pe;
        pv[r] = (short)f2bf(pe);
      }
      *(s16x4*)(&Pw[lr * 72 + tt * 16 + quad * 4]) = pv;
    }
    ps += __shfl_xor(ps, 16);
    ps += __shfl_xor(ps, 32);
    l = l * alpha + ps;
    m = mn;
    float ar[4];
#pragma unroll
    for (int r = 0; r < 4; ++r) ar[r] = __shfl(alpha, quad * 4 + r);
#pragma unroll
    for (int jj = 0; jj < 4; ++jj)
#pragma unroll
      for (int r = 0; r < 4; ++r) o[jj][r] *= ar[r];
#pragma unroll
    for (int sh = 0; sh < 2; ++sh) {
      bf16x8 pa = *(const bf16x8*)(&Pw[lr * 72 + sh * 32 + quad * 8]);
#pragma unroll
      for (int jj = 0; jj < 4; ++jj) {
        bf16x8 vbf = *(const bf16x8*)(&Vs[pp][(jj * 16 + lr) * 64 + (((sh * 4 + quad) ^ sw)) * 8]);
        o[jj] = MFMA16(pa, vbf, o[jj]);
      }
    }
  }
  float inv = 1.f / l;
  float ir[4];
#pragma unroll
  for (int r = 0; r < 4; ++r) ir[r] = __shfl(inv, quad * 4 + r);
  const int h = bh & 15;
#pragma unroll
  for (int r = 0; r < 4; ++r) {
    int slot = q0 + quad * 4 + r;
    if (slot < nv) {
      size_t rowb = ((size_t)(b * 1024 + slot)) * 1024 + h * 64;
#pragma unroll
      for (int jj = 0; jj < 4; ++jj)
        aoc[rowb + jj * 16 + lr] = f2bf(o[jj][r] * ir[r]);
    }
  }
}

// ===== FIN: gemm_out (blocks 0..511) | bias fill of masked rows (blocks 512..767) =====
__global__ __launch_bounds__(256) void k_gemm_fin(
    const unsigned short* __restrict__ A, const unsigned short* __restrict__ Bt,
    const unsigned short* __restrict__ perm, const int* __restrict__ nvb,
    const float* __restrict__ bias, float* __restrict__ C) {
  __shared__ unsigned short SH[24576];        // 48 KB: 2 x (As[64][64] | Bs[128][64])
  const int lid = blockIdx.x;
  const int t = threadIdx.x;
  if (lid >= 512) {
    // ---- masked-row bias fill
    const int idx = lid - 512;
    const int b = idx >> 6, ch = idx & 63;
    const int nv = nvb[b];
    const float4 bv = ((const float4*)bias)[t];
    for (int s = nv + ch * 8; s < 1024; s += 512) {
#pragma unroll
      for (int j = 0; j < 8; ++j) {
        int slot = s + j;
        if (slot < 1024) {
          int tok = perm[b * 1024 + slot];
          ((float4*)(C + ((size_t)(b * 1024 + tok)) * 1024))[t] = bv;
        }
      }
    }
    return;
  }
  const int col = lid & 7;                    // XCD-affine col tile
  const int rt = lid >> 3;
  const int b = rt >> 4, mt = rt & 15;
  const int nv = nvb[b];
  if (mt * 64 >= nv) return;
  const int bm0 = mt * 64;
  const int bn0 = col * 128;
  const size_t abase = ((size_t)(b * 1024 + bm0)) * 1024;
  const int lane = t & 63, wave = t >> 6;
  const int wm = (wave >> 1) * 32, wn = (wave & 1) * 64;
  const int lr = lane & 15, quad = lane >> 4;
  const int sw = lr & 7;
  f32x4 acc[2][4] = {};
  auto stage = [&](int pp, int k0) {
    unsigned short* As = SH + pp * 12288;
    unsigned short* Bs = As + 4096;
#pragma unroll
    for (int j = 0; j < 2; ++j) {
      int idx = t + j * 256;
      int row = idx >> 3;
      int g = (idx ^ row) & 7;
      ASYNC16(&A[abase + (size_t)row * 1024 + k0 + g * 8], &As[idx * 8]);
    }
#pragma unroll
    for (int j = 0; j < 4; ++j) {
      int idx = t + j * 256;
      int row = idx >> 3;
      int g = (idx ^ row) & 7;
      ASYNC16(&Bt[((size_t)(bn0 + row)) * 1024 + k0 + g * 8], &Bs[idx * 8]);
    }
  };
  stage(0, 0);
  for (int it = 0; it < 16; ++it) {
    const int pp = it & 1;
    __syncthreads();
    if (it + 1 < 16) stage(1 - pp, (it + 1) * 64);
    const unsigned short* As = SH + pp * 12288;
    const unsigned short* Bs = As + 4096;
#pragma unroll
    for (int ks = 0; ks < 2; ++ks) {
      bf16x8 af[2], bfr[4];
#pragma unroll
      for (int i = 0; i < 2; ++i)
        af[i] = *(const bf16x8*)(&As[(wm + i * 16 + lr) * 64 + (((ks * 4 + quad) ^ sw)) * 8]);
#pragma unroll
      for (int j = 0; j < 4; ++j)
        bfr[j] = *(const bf16x8*)(&Bs[(wn + j * 16 + lr) * 64 + (((ks * 4 + quad) ^ sw)) * 8]);
#pragma unroll
      for (int i = 0; i < 2; ++i)
#pragma unroll
        for (int j = 0; j < 4; ++j)
          acc[i][j] = MFMA16(af[i], bfr[j], acc[i][j]);
    }
  }
#pragma unroll
  for (int i = 0; i < 2; ++i)
#pragma unroll
    for (int r = 0; r < 4; ++r) {
      int slot = bm0 + wm + i * 16 + quad * 4 + r;
      if (slot < nv) {
        int tok = perm[b * 1024 + slot];
        size_t rowb = ((size_t)(b * 1024 + tok)) * 1024;
#pragma unroll
        for (int j = 0; j < 4; ++j) {
          int c = bn0 + wn + j * 16 + lr;
          C[rowb + c] = acc[i][j][r] + bias[c];
        }
      }
    }
}

extern "C" void kernel_launch(void* const* d_in, const int* in_sizes, int n_in,
                              void* d_out, int out_size, void* d_ws, size_t ws_size,
                              hipStream_t stream) {
  const float* x    = (const float*)d_in[0];
  const float* mask = (const float*)d_in[1];
  const float* wqkv = (const float*)d_in[2];
  const float* wout = (const float*)d_in[3];
  const float* bout = (const float*)d_in[4];
  float* out = (float*)d_out;
  char* ws = (char*)d_ws;
  // layout (40 MB + 8.2 KB):
  unsigned short* xc    = (unsigned short*)(ws);                      // [0,8)  compacted x (dead after gemm1)
  unsigned short* aoc   = (unsigned short*)(ws);                      //        alias: attn out compact
  unsigned short* wqkvt = (unsigned short*)(ws + (size_t)( 8 << 20)); // [8,14)
  unsigned short* woutt = (unsigned short*)(ws + (size_t)(14 << 20)); // [14,16)
  unsigned short* qcmp  = (unsigned short*)(ws + (size_t)(16 << 20)); // [16,24)
  unsigned short* kcmp  = (unsigned short*)(ws + (size_t)(24 << 20)); // [24,32)
  unsigned short* vt    = (unsigned short*)(ws + (size_t)(32 << 20)); // [32,40) V^T compact [bh][d][slot]
  unsigned short* perm  = (unsigned short*)(ws + (size_t)(40 << 20));           // 8 KB
  int*            nvb   = (int*)           (ws + (size_t)(40 << 20) + 8192);    // 16 B

  k_prep<<<5124, 256, 0, stream>>>(x, mask, wqkv, wout, xc, wqkvt, woutt, perm, nvb);
  k_gemm_qkv<<<768, 256, 0, stream>>>(xc, wqkvt, nvb, qcmp, kcmp, vt);
  k_attn<<<1024, 256, 0, stream>>>(qcmp, kcmp, vt, nvb, aoc);
  k_gemm_fin<<<768, 256, 0, stream>>>(aoc, woutt, perm, nvb, bout, out);
}